// Round 3
// baseline (1322.648 us; speedup 1.0000x reference)
//
#include <hip/hip_runtime.h>

// ---------------------------------------------------------------------------
// CriticNetwork: 2x GCNConv (relu) + MLP head + per-graph mean.
// Round 3:
//  - atomic-free deterministic coarse counting sort (LDS-binned, 128-node
//    buckets, packed codes (dstLocal<<17)|src)
//  - per-bucket LDS-accumulator aggregation (no global atomics, no fine CSR)
//  - layer-2 aggregation moved BEFORE the W2 transform (A(ZW)= (AZ)W), so both
//    gathers run in 32-dim; W2+MLP fused into one grid-strided tail kernel.
// ---------------------------------------------------------------------------

#define CHUNK 16384   // edges per sort block
#define BKN   128     // nodes per coarse bucket
#define NBMAX 1024    // max coarse buckets (N <= 131072)

__global__ void k_zero_out(float* out, int n) {
    int i = blockIdx.x * blockDim.x + threadIdx.x;
    if (i < n) out[i] = 0.0f;
}

// ---- coarse counting sort ------------------------------------------------

// per-chunk histogram of dst>>7 into table[b*nblk + chunk]
__global__ __launch_bounds__(256) void k_count_coarse(
    const int* __restrict__ dst, int* __restrict__ table, int E, int nblk, int NB)
{
    __shared__ int cnt[NBMAX];
    const int tid = threadIdx.x;
    for (int i = tid; i < NB; i += 256) cnt[i] = 0;
    __syncthreads();
    const int base = blockIdx.x * CHUNK;
    const int lim = min(CHUNK, E - base);
    for (int i = tid; i < lim; i += 256) atomicAdd(&cnt[dst[base + i] >> 7], 1);
    __syncthreads();
    for (int b = tid; b < NB; b += 256) table[b * nblk + blockIdx.x] = cnt[b];
}

// inclusive block-scan of table -> S[i+1]; block totals -> bsums
__global__ __launch_bounds__(256) void k_scan1(const int* __restrict__ cnts, int* __restrict__ S,
                                               int* __restrict__ bsums, int T) {
    __shared__ int sh[256];
    int t = threadIdx.x;
    int i = blockIdx.x * 256 + t;
    int v = (i < T) ? cnts[i] : 0;
    sh[t] = v;
    __syncthreads();
    for (int off = 1; off < 256; off <<= 1) {
        int tv = (t >= off) ? sh[t - off] : 0;
        __syncthreads();
        sh[t] += tv;
        __syncthreads();
    }
    if (i < T) S[i + 1] = sh[t];
    if (t == 255) bsums[blockIdx.x] = sh[255];
}

__global__ __launch_bounds__(512) void k_scan2(int* bs, int nb) {
    __shared__ int sh[512];
    int t = threadIdx.x;
    int v = (t < nb) ? bs[t] : 0;
    sh[t] = v;
    __syncthreads();
    for (int off = 1; off < 512; off <<= 1) {
        int tv = (t >= off) ? sh[t - off] : 0;
        __syncthreads();
        sh[t] += tv;
        __syncthreads();
    }
    if (t < nb) bs[t] = sh[t] - v;  // exclusive
}

__global__ void k_scan3(int* __restrict__ S, const int* __restrict__ bs, int T) {
    int i = blockIdx.x * blockDim.x + threadIdx.x;
    if (i < T) S[i + 1] += bs[i >> 8];
    if (i == 0) S[0] = 0;
}

// scatter: zero global atomics; rank via LDS atomic; base from scanned table
__global__ __launch_bounds__(256) void k_scatter2(
    const int* __restrict__ ei, const int* __restrict__ S,
    int* __restrict__ codes, int E, int nblk, int NB)
{
    __shared__ int cur[NBMAX];
    const int tid = threadIdx.x;
    for (int i = tid; i < NB; i += 256) cur[i] = 0;
    __syncthreads();
    const int base = blockIdx.x * CHUNK;
    const int lim = min(CHUNK, E - base);
    for (int i = tid; i < lim; i += 256) {
        int e = base + i;
        int s = ei[e], d = ei[E + e];
        int b = d >> 7;
        int r = atomicAdd(&cur[b], 1);
        codes[S[b * nblk + blockIdx.x] + r] = ((d & 127) << 17) | s;
    }
}

// per-bucket fine degree count -> dinv = rsqrt(1 + indeg)
__global__ __launch_bounds__(256) void k_bucket_dinv(
    const int* __restrict__ codes, const int* __restrict__ S,
    float* __restrict__ dinv, int nblk, int N)
{
    __shared__ int cnt[BKN];
    const int tid = threadIdx.x;
    if (tid < BKN) cnt[tid] = 0;
    __syncthreads();
    const int b = blockIdx.x;
    const int beg = S[b * nblk], end = S[(b + 1) * nblk];
    for (int e = beg + tid; e < end; e += 256) atomicAdd(&cnt[codes[e] >> 17], 1);
    __syncthreads();
    int n = b * BKN + tid;
    if (tid < BKN && n < N) dinv[n] = rsqrtf(1.0f + (float)cnt[tid]);
}

// ---- dense compute -------------------------------------------------------

// hs1 = (x @ W1) * dinv   (N x 128 @ 128 x 32)
__global__ __launch_bounds__(256) void k_gemm1(
    const float* __restrict__ x, const float* __restrict__ W,
    const float* __restrict__ dinv, float* __restrict__ hs1, int N)
{
    __shared__ float Wl[128 * 32];
    __shared__ __align__(16) float Xl[8 * 132];
    const int tid = threadIdx.x;
    for (int i = tid; i < 128 * 32; i += 256) Wl[i] = W[i];
    const int node0 = blockIdx.x * 8;
    {
        int r = tid >> 5, c4 = tid & 31;
        int node = node0 + r;
        float4 v = make_float4(0.f, 0.f, 0.f, 0.f);
        if (node < N) v = ((const float4*)(x + (size_t)node * 128))[c4];
        *(float4*)&Xl[r * 132 + c4 * 4] = v;
    }
    __syncthreads();
    const int row = tid >> 5, f = tid & 31;
    float acc = 0.f;
#pragma unroll
    for (int k = 0; k < 128; k += 4) {
        float4 xv = *(const float4*)&Xl[row * 132 + k];
        acc += xv.x * Wl[(k + 0) * 32 + f];
        acc += xv.y * Wl[(k + 1) * 32 + f];
        acc += xv.z * Wl[(k + 2) * 32 + f];
        acc += xv.w * Wl[(k + 3) * 32 + f];
    }
    const int node = node0 + row;
    if (node < N) hs1[(size_t)node * 32 + f] = acc * dinv[node];
}

// per-bucket LDS-accumulate aggregation over sorted codes.
// L1: OUT = relu(dinv*(IN[self]+sum) + bias) * dinv   (produces Zs for layer 2)
// L2: OUT = dinv*(IN[self]+sum)                        (= A_hat . Z1, pre-W2)
template <bool L1>
__global__ __launch_bounds__(256) void k_aggX(
    const int* __restrict__ codes, const int* __restrict__ S,
    const float* __restrict__ IN, const float* __restrict__ bias,
    const float* __restrict__ dinv, float* __restrict__ OUT, int nblk, int N)
{
    __shared__ float acc[BKN * 32];   // 16 KB
    const int tid = threadIdx.x;
    for (int i = tid; i < BKN * 32; i += 256) acc[i] = 0.f;
    __syncthreads();
    const int b = blockIdx.x;
    const int beg = S[b * nblk], end = S[(b + 1) * nblk];
    const int g = tid >> 5, f = tid & 31;
    int e = beg + g;
    for (; e + 24 < end; e += 32) {
        int c0 = codes[e], c1 = codes[e + 8], c2 = codes[e + 16], c3 = codes[e + 24];
        float v0 = IN[(size_t)(c0 & 0x1FFFF) * 32 + f];
        float v1 = IN[(size_t)(c1 & 0x1FFFF) * 32 + f];
        float v2 = IN[(size_t)(c2 & 0x1FFFF) * 32 + f];
        float v3 = IN[(size_t)(c3 & 0x1FFFF) * 32 + f];
        atomicAdd(&acc[(c0 >> 17) * 32 + f], v0);
        atomicAdd(&acc[(c1 >> 17) * 32 + f], v1);
        atomicAdd(&acc[(c2 >> 17) * 32 + f], v2);
        atomicAdd(&acc[(c3 >> 17) * 32 + f], v3);
    }
    for (; e < end; e += 8) {
        int c = codes[e];
        atomicAdd(&acc[(c >> 17) * 32 + f], IN[(size_t)(c & 0x1FFFF) * 32 + f]);
    }
    __syncthreads();
    const int n0 = b * BKN;
    for (int i = tid; i < BKN * 32; i += 256) {
        int nl = i >> 5, ff = i & 31, n = n0 + nl;
        if (n < N) {
            float dv = dinv[n];
            float v = dv * (IN[(size_t)n * 32 + ff] + acc[i]);
            if (L1) v = fmaxf(v + bias[ff], 0.f) * dv;
            OUT[(size_t)n * 32 + ff] = v;
        }
    }
}

// fused tail: per node v = relu(relu(Y@W2+b2)@Wm1+bm1)@Wm2+bm2.
// grid-strided; each wave handles 4 nodes per round (amortizes LDS weight reads).
__global__ __launch_bounds__(256) void k_tail(
    const float* __restrict__ Y, const float* __restrict__ W2, const float* __restrict__ b2,
    const float* __restrict__ Wm1, const float* __restrict__ bm1,
    const float* __restrict__ Wm2, const float* __restrict__ bm2,
    float* __restrict__ vtmp, int N, int nrounds)
{
    __shared__ float W2l[32 * 64];
    __shared__ float W1l[64 * 64];
    __shared__ float b2l[64], bm1l[64], w2v[64];
    __shared__ __align__(16) float ybuf[4][4][32];
    __shared__ __align__(16) float zbuf[4][4][64];
    const int tid = threadIdx.x;
    for (int i = tid; i < 32 * 64; i += 256) W2l[i] = W2[i];
    for (int i = tid; i < 64 * 64; i += 256) W1l[i] = Wm1[i];
    if (tid < 64) { b2l[tid] = b2[tid]; bm1l[tid] = bm1[tid]; w2v[tid] = Wm2[tid]; }
    __syncthreads();
    const int wid = tid >> 6, lane = tid & 63;
    const float bm2v = bm2[0];
    for (int r = 0; r < nrounds; ++r) {
        const int base = (blockIdx.x + r * gridDim.x) * 16 + wid * 4;
        // stage 4 Y rows (wave-private LDS; ds ops in-order within a wave)
        for (int j = lane; j < 128; j += 64) {
            int nd = j >> 5, k = j & 31, n = base + nd;
            ybuf[wid][nd][k] = (n < N) ? Y[(size_t)n * 32 + k] : 0.f;
        }
        float h0 = b2l[lane], h1 = h0, h2 = h0, h3 = h0;
#pragma unroll
        for (int k = 0; k < 32; k += 4) {
            float w0 = W2l[(k + 0) * 64 + lane], w1 = W2l[(k + 1) * 64 + lane];
            float w2 = W2l[(k + 2) * 64 + lane], w3 = W2l[(k + 3) * 64 + lane];
            float4 ya = *(const float4*)&ybuf[wid][0][k];
            float4 yb = *(const float4*)&ybuf[wid][1][k];
            float4 yc = *(const float4*)&ybuf[wid][2][k];
            float4 yd = *(const float4*)&ybuf[wid][3][k];
            h0 += ya.x * w0 + ya.y * w1 + ya.z * w2 + ya.w * w3;
            h1 += yb.x * w0 + yb.y * w1 + yb.z * w2 + yb.w * w3;
            h2 += yc.x * w0 + yc.y * w1 + yc.z * w2 + yc.w * w3;
            h3 += yd.x * w0 + yd.y * w1 + yd.z * w2 + yd.w * w3;
        }
        zbuf[wid][0][lane] = fmaxf(h0, 0.f);
        zbuf[wid][1][lane] = fmaxf(h1, 0.f);
        zbuf[wid][2][lane] = fmaxf(h2, 0.f);
        zbuf[wid][3][lane] = fmaxf(h3, 0.f);
        float t0 = bm1l[lane], t1 = t0, t2 = t0, t3 = t0;
#pragma unroll
        for (int k = 0; k < 64; k += 4) {
            float w0 = W1l[(k + 0) * 64 + lane], w1 = W1l[(k + 1) * 64 + lane];
            float w2 = W1l[(k + 2) * 64 + lane], w3 = W1l[(k + 3) * 64 + lane];
            float4 za = *(const float4*)&zbuf[wid][0][k];
            float4 zb = *(const float4*)&zbuf[wid][1][k];
            float4 zc = *(const float4*)&zbuf[wid][2][k];
            float4 zd = *(const float4*)&zbuf[wid][3][k];
            t0 += za.x * w0 + za.y * w1 + za.z * w2 + za.w * w3;
            t1 += zb.x * w0 + zb.y * w1 + zb.z * w2 + zb.w * w3;
            t2 += zc.x * w0 + zc.y * w1 + zc.z * w2 + zc.w * w3;
            t3 += zd.x * w0 + zd.y * w1 + zd.z * w2 + zd.w * w3;
        }
        float v0 = fmaxf(t0, 0.f) * w2v[lane];
        float v1 = fmaxf(t1, 0.f) * w2v[lane];
        float v2 = fmaxf(t2, 0.f) * w2v[lane];
        float v3 = fmaxf(t3, 0.f) * w2v[lane];
#pragma unroll
        for (int off = 32; off > 0; off >>= 1) {
            v0 += __shfl_down(v0, off, 64);
            v1 += __shfl_down(v1, off, 64);
            v2 += __shfl_down(v2, off, 64);
            v3 += __shfl_down(v3, off, 64);
        }
        if (lane == 0) {
            if (base + 0 < N) vtmp[base + 0] = v0 + bm2v;
            if (base + 1 < N) vtmp[base + 1] = v1 + bm2v;
            if (base + 2 < N) vtmp[base + 2] = v2 + bm2v;
            if (base + 3 < N) vtmp[base + 3] = v3 + bm2v;
        }
    }
}

__global__ void k_reduce(const float* __restrict__ v, const int* __restrict__ num_nodes_p,
                         float* out, int N, int n_graphs)
{
    __shared__ float acc[32];
    int tid = threadIdx.x;
    if (tid < n_graphs) acc[tid] = 0.f;
    __syncthreads();
    int i = blockIdx.x * blockDim.x + tid;
    int nn = num_nodes_p[0];
    if (i < N) {
        int g = i / nn;
        if (g < n_graphs) atomicAdd(&acc[g], v[i]);
    }
    __syncthreads();
    if (tid < n_graphs) atomicAdd(&out[tid], acc[tid] / (float)nn);
}

// ---- fallback (atomic) path ----------------------------------------------
__global__ void k_zero_int(int* p, int n) {
    int i = blockIdx.x * blockDim.x + threadIdx.x;
    if (i < n) p[i] = 0;
}
__global__ void k_hist(const int* __restrict__ dst, int* __restrict__ deg, int E) {
    int e = blockIdx.x * blockDim.x + threadIdx.x;
    if (e < E) atomicAdd(&deg[dst[e]], 1);
}
__global__ void k_dinv(const int* __restrict__ deg, float* __restrict__ dinv, int n) {
    int i = blockIdx.x * blockDim.x + threadIdx.x;
    if (i < n) dinv[i] = rsqrtf(1.0f + (float)deg[i]);
}
__global__ __launch_bounds__(256) void k_gemm2(
    const float* __restrict__ agg1, const float* __restrict__ W,
    const float* __restrict__ dinv, float* __restrict__ hs2, int N)
{
    __shared__ float Wl[32 * 64];
    __shared__ __align__(16) float Zl[4 * 36];
    const int tid = threadIdx.x;
    for (int i = tid; i < 32 * 64; i += 256) Wl[i] = W[i];
    const int node0 = blockIdx.x * 4;
    if (tid < 128) {
        int r = tid >> 5, c = tid & 31;
        int node = node0 + r;
        float v = 0.f;
        if (node < N) v = fmaxf(agg1[(size_t)node * 32 + c], 0.f);
        Zl[r * 36 + c] = v;
    }
    __syncthreads();
    const int row = tid >> 6, f = tid & 63;
    float acc = 0.f;
#pragma unroll
    for (int k = 0; k < 32; k += 4) {
        float4 zv = *(const float4*)&Zl[row * 36 + k];
        acc += zv.x * Wl[(k + 0) * 64 + f];
        acc += zv.y * Wl[(k + 1) * 64 + f];
        acc += zv.z * Wl[(k + 2) * 64 + f];
        acc += zv.w * Wl[(k + 3) * 64 + f];
    }
    int node = node0 + row;
    if (node < N) {
        float dv = dinv[node];
        hs2[(size_t)node * 64 + f] = acc * dv;
    }
}
template <int F>
__global__ void k_agg_init(const float* __restrict__ hs, const float* __restrict__ b,
                           const float* __restrict__ dinv, float* __restrict__ agg, int N)
{
    long long t = (long long)blockIdx.x * blockDim.x + threadIdx.x;
    int n = (int)(t / F), f = (int)(t % F);
    if (n < N) agg[(size_t)n * F + f] = hs[(size_t)n * F + f] * dinv[n] + b[f];
}
template <int F>
__global__ void k_edge_atomic(const int* __restrict__ ei, const float* __restrict__ hs,
                              const float* __restrict__ dinv, float* __restrict__ agg, int E)
{
    long long tid = (long long)blockIdx.x * blockDim.x + threadIdx.x;
    int e = (int)(tid / F), f = (int)(tid % F);
    if (e < E) {
        int s = ei[e], d = ei[E + e];
        atomicAdd(&agg[(size_t)d * F + f], hs[(size_t)s * F + f] * dinv[d]);
    }
}
__global__ __launch_bounds__(256) void k_mlp(
    const float* __restrict__ agg2, const float* __restrict__ Wm1,
    const float* __restrict__ bm1, const float* __restrict__ Wm2,
    const float* __restrict__ bm2, float* __restrict__ vout, int N)
{
    __shared__ float Wl[64 * 64];
    __shared__ float W2l[64];
    __shared__ __align__(16) float Zl[4][64];
    const int tid = threadIdx.x;
    for (int i = tid; i < 64 * 64; i += 256) Wl[i] = Wm1[i];
    if (tid < 64) W2l[tid] = Wm2[tid];
    const int wid = tid >> 6, lane = tid & 63;
    const int node = blockIdx.x * 4 + wid;
    float zv = 0.f;
    if (node < N) zv = fmaxf(agg2[(size_t)node * 64 + lane], 0.f);
    Zl[wid][lane] = zv;
    __syncthreads();
    float t = bm1[lane];
#pragma unroll
    for (int k = 0; k < 64; k += 4) {
        float4 z4 = *(const float4*)&Zl[wid][k];
        t += z4.x * Wl[(k + 0) * 64 + lane];
        t += z4.y * Wl[(k + 1) * 64 + lane];
        t += z4.z * Wl[(k + 2) * 64 + lane];
        t += z4.w * Wl[(k + 3) * 64 + lane];
    }
    t = fmaxf(t, 0.f);
    float val = t * W2l[lane];
#pragma unroll
    for (int off = 32; off > 0; off >>= 1) val += __shfl_down(val, off, 64);
    if (lane == 0 && node < N) vout[node] = val + bm2[0];
}
// ---------------------------------------------------------------------------

extern "C" void kernel_launch(void* const* d_in, const int* in_sizes, int n_in,
                              void* d_out, int out_size, void* d_ws, size_t ws_size,
                              hipStream_t stream)
{
    const float* x   = (const float*)d_in[0];
    const float* W1  = (const float*)d_in[1];
    const float* b1  = (const float*)d_in[2];
    const float* W2  = (const float*)d_in[3];
    const float* b2  = (const float*)d_in[4];
    const float* Wm1 = (const float*)d_in[5];
    const float* bm1 = (const float*)d_in[6];
    const float* Wm2 = (const float*)d_in[7];
    const float* bm2 = (const float*)d_in[8];
    const int*   ei  = (const int*)d_in[9];
    const int*   nn  = (const int*)d_in[10];
    const int N = in_sizes[0] / 128;
    const int E = in_sizes[9] / 2;
    float* out = (float*)d_out;

    const int NB = (N + BKN - 1) / BKN;
    const int nblk = (E + CHUNK - 1) / CHUNK;
    const long long T = (long long)NB * nblk;
    const int nb1 = (int)((T + 255) / 256);
    const size_t need_ints = (size_t)T /*table*/ + (size_t)(T + 1) /*S*/ + 512 /*bsums*/
                           + (size_t)E /*codes*/ + (size_t)N /*dinv*/
                           + 96ull * N /*hs1,Zs,Y*/ + (size_t)N /*vtmp*/;
    const bool use_new = (N <= 131072) && (T <= 131072) && (nb1 <= 512)
                       && (ws_size >= need_ints * sizeof(int));

    k_zero_out<<<1, 64, 0, stream>>>(out, out_size);

    if (use_new) {
        int*   table = (int*)d_ws;                 // T
        int*   S     = table + T;                  // T+1
        int*   bsums = S + (T + 1);                // 512
        int*   codes = bsums + 512;                // E
        float* dinv  = (float*)(codes + E);        // N
        float* hs1   = dinv + N;                   // 32N
        float* Zs    = hs1 + 32 * (size_t)N;       // 32N
        float* Y     = Zs + 32 * (size_t)N;        // 32N
        float* vtmp  = Y + 32 * (size_t)N;         // N

        k_count_coarse<<<nblk, 256, 0, stream>>>(ei + E, table, E, nblk, NB);
        k_scan1<<<nb1, 256, 0, stream>>>(table, S, bsums, (int)T);
        k_scan2<<<1, 512, 0, stream>>>(bsums, nb1);
        k_scan3<<<nb1, 256, 0, stream>>>(S, bsums, (int)T);
        k_scatter2<<<nblk, 256, 0, stream>>>(ei, S, codes, E, nblk, NB);
        k_bucket_dinv<<<NB, 256, 0, stream>>>(codes, S, dinv, nblk, N);
        k_gemm1<<<(N + 7) / 8, 256, 0, stream>>>(x, W1, dinv, hs1, N);
        k_aggX<true><<<NB, 256, 0, stream>>>(codes, S, hs1, b1, dinv, Zs, nblk, N);
        k_aggX<false><<<NB, 256, 0, stream>>>(codes, S, Zs, b1, dinv, Y, nblk, N);
        const int tgrid = 1024;
        const int nrounds = (N + tgrid * 16 - 1) / (tgrid * 16);
        k_tail<<<tgrid, 256, 0, stream>>>(Y, W2, b2, Wm1, bm1, Wm2, bm2, vtmp, N, nrounds);
        k_reduce<<<(N + 255) / 256, 256, 0, stream>>>(vtmp, nn, out, N, out_size);
    } else {
        // fallback: atomic scatter path
        const size_t Ns = (size_t)N;
        float* dinv = (float*)d_ws;
        float* B    = dinv + N;
        float* hs1  = B;
        float* agg1 = B + 32 * Ns;
        float* hs2  = B + 64 * Ns;
        float* agg2 = B + 128 * Ns;
        float* vtmp = B;
        int*   deg  = (int*)B;

        const int nb = (N + 255) / 256;
        k_zero_int<<<nb, 256, 0, stream>>>(deg, N);
        k_hist<<<(E + 255) / 256, 256, 0, stream>>>(ei + E, deg, E);
        k_dinv<<<nb, 256, 0, stream>>>(deg, dinv, N);
        k_gemm1<<<(N + 7) / 8, 256, 0, stream>>>(x, W1, dinv, hs1, N);
        {
            long long t = (long long)N * 32;
            k_agg_init<32><<<(unsigned)((t + 255) / 256), 256, 0, stream>>>(hs1, b1, dinv, agg1, N);
            t = (long long)E * 32;
            k_edge_atomic<32><<<(unsigned)((t + 255) / 256), 256, 0, stream>>>(ei, hs1, dinv, agg1, E);
        }
        k_gemm2<<<(N + 3) / 4, 256, 0, stream>>>(agg1, W2, dinv, hs2, N);
        {
            long long t = (long long)N * 64;
            k_agg_init<64><<<(unsigned)((t + 255) / 256), 256, 0, stream>>>(hs2, b2, dinv, agg2, N);
            t = (long long)E * 64;
            k_edge_atomic<64><<<(unsigned)((t + 255) / 256), 256, 0, stream>>>(ei, hs2, dinv, agg2, E);
        }
        k_mlp<<<(N + 3) / 4, 256, 0, stream>>>(agg2, Wm1, bm1, Wm2, bm2, vtmp, N);
        k_reduce<<<nb, 256, 0, stream>>>(vtmp, nn, out, N, out_size);
    }
}

// Round 4
// 433.636 us; speedup vs baseline: 3.0501x; 3.0501x over previous
//
#include <hip/hip_runtime.h>

// ---------------------------------------------------------------------------
// CriticNetwork: 2x GCNConv (relu) + MLP head + per-graph mean.
// Round 4: coarse atomic-free counting sort (round 3) + per-bucket fine CSR
// (k_fine) + node-parallel float4 CSR gather (round-2 structure, 4x vectorized).
// Both aggregations in 32-dim via A(ZW2)=(AZ)W2; W2+MLP fused in k_tail.
// ---------------------------------------------------------------------------

#define CHUNK 16384   // edges per sort block
#define BKN   128     // nodes per coarse bucket
#define NBMAX 1024    // max coarse buckets (N <= 131072)

__global__ void k_zero_out(float* out, int n) {
    int i = blockIdx.x * blockDim.x + threadIdx.x;
    if (i < n) out[i] = 0.0f;
}

// ---- coarse counting sort ------------------------------------------------

__global__ __launch_bounds__(256) void k_count_coarse(
    const int* __restrict__ dst, int* __restrict__ table, int E, int nblk, int NB)
{
    __shared__ int cnt[NBMAX];
    const int tid = threadIdx.x;
    for (int i = tid; i < NB; i += 256) cnt[i] = 0;
    __syncthreads();
    const int base = blockIdx.x * CHUNK;
    const int lim = min(CHUNK, E - base);
    for (int i = tid; i < lim; i += 256) atomicAdd(&cnt[dst[base + i] >> 7], 1);
    __syncthreads();
    for (int b = tid; b < NB; b += 256) table[b * nblk + blockIdx.x] = cnt[b];
}

__global__ __launch_bounds__(256) void k_scan1(const int* __restrict__ cnts, int* __restrict__ S,
                                               int* __restrict__ bsums, int T) {
    __shared__ int sh[256];
    int t = threadIdx.x;
    int i = blockIdx.x * 256 + t;
    int v = (i < T) ? cnts[i] : 0;
    sh[t] = v;
    __syncthreads();
    for (int off = 1; off < 256; off <<= 1) {
        int tv = (t >= off) ? sh[t - off] : 0;
        __syncthreads();
        sh[t] += tv;
        __syncthreads();
    }
    if (i < T) S[i + 1] = sh[t];
    if (t == 255) bsums[blockIdx.x] = sh[255];
}

__global__ __launch_bounds__(512) void k_scan2(int* bs, int nb) {
    __shared__ int sh[512];
    int t = threadIdx.x;
    int v = (t < nb) ? bs[t] : 0;
    sh[t] = v;
    __syncthreads();
    for (int off = 1; off < 512; off <<= 1) {
        int tv = (t >= off) ? sh[t - off] : 0;
        __syncthreads();
        sh[t] += tv;
        __syncthreads();
    }
    if (t < nb) bs[t] = sh[t] - v;  // exclusive
}

__global__ void k_scan3(int* __restrict__ S, const int* __restrict__ bs, int T) {
    int i = blockIdx.x * blockDim.x + threadIdx.x;
    if (i < T) S[i + 1] += bs[i >> 8];
    if (i == 0) S[0] = 0;
}

__global__ __launch_bounds__(256) void k_scatter2(
    const int* __restrict__ ei, const int* __restrict__ S,
    int* __restrict__ codes, int E, int nblk, int NB)
{
    __shared__ int cur[NBMAX];
    const int tid = threadIdx.x;
    for (int i = tid; i < NB; i += 256) cur[i] = 0;
    __syncthreads();
    const int base = blockIdx.x * CHUNK;
    const int lim = min(CHUNK, E - base);
    for (int i = tid; i < lim; i += 256) {
        int e = base + i;
        int s = ei[e], d = ei[E + e];
        int b = d >> 7;
        int r = atomicAdd(&cur[b], 1);
        codes[S[b * nblk + blockIdx.x] + r] = ((d & 127) << 17) | s;
    }
}

// per-bucket fine CSR: degree count -> LDS scan -> dst-sorted esrc + row_start + dinv
__global__ __launch_bounds__(256) void k_fine(
    const int* __restrict__ codes, const int* __restrict__ S,
    int* __restrict__ esrc, int* __restrict__ row_start,
    float* __restrict__ dinv, int nblk, int N, int E, int NB)
{
    __shared__ int cnt[BKN];
    __shared__ int sh[BKN];
    __shared__ int cur[BKN];
    const int tid = threadIdx.x;
    if (tid < BKN) cnt[tid] = 0;
    __syncthreads();
    const int b = blockIdx.x;
    const int beg = S[b * nblk], end = S[(b + 1) * nblk];
    for (int e = beg + tid; e < end; e += 256) atomicAdd(&cnt[codes[e] >> 17], 1);
    __syncthreads();
    if (tid < BKN) sh[tid] = cnt[tid];
    __syncthreads();
    for (int off = 1; off < BKN; off <<= 1) {
        int tv = (tid >= off && tid < BKN) ? sh[tid - off] : 0;
        __syncthreads();
        if (tid < BKN) sh[tid] += tv;
        __syncthreads();
    }
    if (tid < BKN) {
        int fs = beg + sh[tid] - cnt[tid];   // exclusive prefix, global offset
        cur[tid] = fs;
        int n = b * BKN + tid;
        if (n < N) {
            row_start[n] = fs;
            dinv[n] = rsqrtf(1.0f + (float)cnt[tid]);
        }
    }
    if (b == NB - 1 && tid == 0) row_start[N] = E;
    __syncthreads();
    for (int e = beg + tid; e < end; e += 256) {
        int c = codes[e];
        int pos = atomicAdd(&cur[c >> 17], 1);
        esrc[pos] = c & 0x1FFFF;
    }
}

// ---- dense compute -------------------------------------------------------

// hs1 = (x @ W1) * dinv   (N x 128 @ 128 x 32)
__global__ __launch_bounds__(256) void k_gemm1(
    const float* __restrict__ x, const float* __restrict__ W,
    const float* __restrict__ dinv, float* __restrict__ hs1, int N)
{
    __shared__ float Wl[128 * 32];
    __shared__ __align__(16) float Xl[8 * 132];
    const int tid = threadIdx.x;
    for (int i = tid; i < 128 * 32; i += 256) Wl[i] = W[i];
    const int node0 = blockIdx.x * 8;
    {
        int r = tid >> 5, c4 = tid & 31;
        int node = node0 + r;
        float4 v = make_float4(0.f, 0.f, 0.f, 0.f);
        if (node < N) v = ((const float4*)(x + (size_t)node * 128))[c4];
        *(float4*)&Xl[r * 132 + c4 * 4] = v;
    }
    __syncthreads();
    const int row = tid >> 5, f = tid & 31;
    float acc = 0.f;
#pragma unroll
    for (int k = 0; k < 128; k += 4) {
        float4 xv = *(const float4*)&Xl[row * 132 + k];
        acc += xv.x * Wl[(k + 0) * 32 + f];
        acc += xv.y * Wl[(k + 1) * 32 + f];
        acc += xv.z * Wl[(k + 2) * 32 + f];
        acc += xv.w * Wl[(k + 3) * 32 + f];
    }
    const int node = node0 + row;
    if (node < N) hs1[(size_t)node * 32 + f] = acc * dinv[node];
}

// node-parallel float4 CSR gather-reduce. 8 lanes per node, 32 nodes/block.
// L1: OUT = relu(dinv*(IN[self]+sum) + bias) * dinv
// L2: OUT = dinv*(IN[self]+sum)
template <bool L1>
__global__ __launch_bounds__(256) void k_agg4(
    const int* __restrict__ row_start, const int* __restrict__ esrc,
    const float* __restrict__ IN, const float* __restrict__ bias,
    const float* __restrict__ dinv, float* __restrict__ OUT, int N)
{
    const int tid = threadIdx.x;
    const int g = tid >> 3, l = tid & 7;       // 32 groups x 8 lanes
    const int n = blockIdx.x * 32 + g;
    if (n >= N) return;
    const float4* IN4 = (const float4*)IN;
    const int beg = row_start[n], end = row_start[n + 1];
    float4 acc = IN4[(size_t)n * 8 + l];       // self-loop term
    int e = beg;
    for (; e + 3 < end; e += 4) {
        int s0 = esrc[e], s1 = esrc[e + 1], s2 = esrc[e + 2], s3 = esrc[e + 3];
        float4 v0 = IN4[(size_t)s0 * 8 + l];
        float4 v1 = IN4[(size_t)s1 * 8 + l];
        float4 v2 = IN4[(size_t)s2 * 8 + l];
        float4 v3 = IN4[(size_t)s3 * 8 + l];
        acc.x += (v0.x + v1.x) + (v2.x + v3.x);
        acc.y += (v0.y + v1.y) + (v2.y + v3.y);
        acc.z += (v0.z + v1.z) + (v2.z + v3.z);
        acc.w += (v0.w + v1.w) + (v2.w + v3.w);
    }
    for (; e < end; ++e) {
        float4 v = IN4[(size_t)esrc[e] * 8 + l];
        acc.x += v.x; acc.y += v.y; acc.z += v.z; acc.w += v.w;
    }
    const float dv = dinv[n];
    float4 o;
    if (L1) {
        float4 b4 = ((const float4*)bias)[l];
        o.x = fmaxf(dv * acc.x + b4.x, 0.f) * dv;
        o.y = fmaxf(dv * acc.y + b4.y, 0.f) * dv;
        o.z = fmaxf(dv * acc.z + b4.z, 0.f) * dv;
        o.w = fmaxf(dv * acc.w + b4.w, 0.f) * dv;
    } else {
        o.x = dv * acc.x; o.y = dv * acc.y; o.z = dv * acc.z; o.w = dv * acc.w;
    }
    ((float4*)OUT)[(size_t)n * 8 + l] = o;
}

// fused tail: per node v = relu(relu(Y@W2+b2)@Wm1+bm1)@Wm2+bm2.
__global__ __launch_bounds__(256) void k_tail(
    const float* __restrict__ Y, const float* __restrict__ W2, const float* __restrict__ b2,
    const float* __restrict__ Wm1, const float* __restrict__ bm1,
    const float* __restrict__ Wm2, const float* __restrict__ bm2,
    float* __restrict__ vtmp, int N, int nrounds)
{
    __shared__ float W2l[32 * 64];
    __shared__ float W1l[64 * 64];
    __shared__ float b2l[64], bm1l[64], w2v[64];
    __shared__ __align__(16) float ybuf[4][4][32];
    __shared__ __align__(16) float zbuf[4][4][64];
    const int tid = threadIdx.x;
    for (int i = tid; i < 32 * 64; i += 256) W2l[i] = W2[i];
    for (int i = tid; i < 64 * 64; i += 256) W1l[i] = Wm1[i];
    if (tid < 64) { b2l[tid] = b2[tid]; bm1l[tid] = bm1[tid]; w2v[tid] = Wm2[tid]; }
    __syncthreads();
    const int wid = tid >> 6, lane = tid & 63;
    const float bm2v = bm2[0];
    for (int r = 0; r < nrounds; ++r) {
        const int base = (blockIdx.x + r * gridDim.x) * 16 + wid * 4;
        for (int j = lane; j < 128; j += 64) {
            int nd = j >> 5, k = j & 31, n = base + nd;
            ybuf[wid][nd][k] = (n < N) ? Y[(size_t)n * 32 + k] : 0.f;
        }
        float h0 = b2l[lane], h1 = h0, h2 = h0, h3 = h0;
#pragma unroll
        for (int k = 0; k < 32; k += 4) {
            float w0 = W2l[(k + 0) * 64 + lane], w1 = W2l[(k + 1) * 64 + lane];
            float w2 = W2l[(k + 2) * 64 + lane], w3 = W2l[(k + 3) * 64 + lane];
            float4 ya = *(const float4*)&ybuf[wid][0][k];
            float4 yb = *(const float4*)&ybuf[wid][1][k];
            float4 yc = *(const float4*)&ybuf[wid][2][k];
            float4 yd = *(const float4*)&ybuf[wid][3][k];
            h0 += ya.x * w0 + ya.y * w1 + ya.z * w2 + ya.w * w3;
            h1 += yb.x * w0 + yb.y * w1 + yb.z * w2 + yb.w * w3;
            h2 += yc.x * w0 + yc.y * w1 + yc.z * w2 + yc.w * w3;
            h3 += yd.x * w0 + yd.y * w1 + yd.z * w2 + yd.w * w3;
        }
        zbuf[wid][0][lane] = fmaxf(h0, 0.f);
        zbuf[wid][1][lane] = fmaxf(h1, 0.f);
        zbuf[wid][2][lane] = fmaxf(h2, 0.f);
        zbuf[wid][3][lane] = fmaxf(h3, 0.f);
        float t0 = bm1l[lane], t1 = t0, t2 = t0, t3 = t0;
#pragma unroll
        for (int k = 0; k < 64; k += 4) {
            float w0 = W1l[(k + 0) * 64 + lane], w1 = W1l[(k + 1) * 64 + lane];
            float w2 = W1l[(k + 2) * 64 + lane], w3 = W1l[(k + 3) * 64 + lane];
            float4 za = *(const float4*)&zbuf[wid][0][k];
            float4 zb = *(const float4*)&zbuf[wid][1][k];
            float4 zc = *(const float4*)&zbuf[wid][2][k];
            float4 zd = *(const float4*)&zbuf[wid][3][k];
            t0 += za.x * w0 + za.y * w1 + za.z * w2 + za.w * w3;
            t1 += zb.x * w0 + zb.y * w1 + zb.z * w2 + zb.w * w3;
            t2 += zc.x * w0 + zc.y * w1 + zc.z * w2 + zc.w * w3;
            t3 += zd.x * w0 + zd.y * w1 + zd.z * w2 + zd.w * w3;
        }
        float v0 = fmaxf(t0, 0.f) * w2v[lane];
        float v1 = fmaxf(t1, 0.f) * w2v[lane];
        float v2 = fmaxf(t2, 0.f) * w2v[lane];
        float v3 = fmaxf(t3, 0.f) * w2v[lane];
#pragma unroll
        for (int off = 32; off > 0; off >>= 1) {
            v0 += __shfl_down(v0, off, 64);
            v1 += __shfl_down(v1, off, 64);
            v2 += __shfl_down(v2, off, 64);
            v3 += __shfl_down(v3, off, 64);
        }
        if (lane == 0) {
            if (base + 0 < N) vtmp[base + 0] = v0 + bm2v;
            if (base + 1 < N) vtmp[base + 1] = v1 + bm2v;
            if (base + 2 < N) vtmp[base + 2] = v2 + bm2v;
            if (base + 3 < N) vtmp[base + 3] = v3 + bm2v;
        }
    }
}

__global__ void k_reduce(const float* __restrict__ v, const int* __restrict__ num_nodes_p,
                         float* out, int N, int n_graphs)
{
    __shared__ float acc[32];
    int tid = threadIdx.x;
    if (tid < n_graphs) acc[tid] = 0.f;
    __syncthreads();
    int i = blockIdx.x * blockDim.x + tid;
    int nn = num_nodes_p[0];
    if (i < N) {
        int g = i / nn;
        if (g < n_graphs) atomicAdd(&acc[g], v[i]);
    }
    __syncthreads();
    if (tid < n_graphs) atomicAdd(&out[tid], acc[tid] / (float)nn);
}

// ---- fallback (atomic) path ----------------------------------------------
__global__ void k_zero_int(int* p, int n) {
    int i = blockIdx.x * blockDim.x + threadIdx.x;
    if (i < n) p[i] = 0;
}
__global__ void k_hist(const int* __restrict__ dst, int* __restrict__ deg, int E) {
    int e = blockIdx.x * blockDim.x + threadIdx.x;
    if (e < E) atomicAdd(&deg[dst[e]], 1);
}
__global__ void k_dinv(const int* __restrict__ deg, float* __restrict__ dinv, int n) {
    int i = blockIdx.x * blockDim.x + threadIdx.x;
    if (i < n) dinv[i] = rsqrtf(1.0f + (float)deg[i]);
}
__global__ __launch_bounds__(256) void k_gemm2(
    const float* __restrict__ agg1, const float* __restrict__ W,
    const float* __restrict__ dinv, float* __restrict__ hs2, int N)
{
    __shared__ float Wl[32 * 64];
    __shared__ __align__(16) float Zl[4 * 36];
    const int tid = threadIdx.x;
    for (int i = tid; i < 32 * 64; i += 256) Wl[i] = W[i];
    const int node0 = blockIdx.x * 4;
    if (tid < 128) {
        int r = tid >> 5, c = tid & 31;
        int node = node0 + r;
        float v = 0.f;
        if (node < N) v = fmaxf(agg1[(size_t)node * 32 + c], 0.f);
        Zl[r * 36 + c] = v;
    }
    __syncthreads();
    const int row = tid >> 6, f = tid & 63;
    float acc = 0.f;
#pragma unroll
    for (int k = 0; k < 32; k += 4) {
        float4 zv = *(const float4*)&Zl[row * 36 + k];
        acc += zv.x * Wl[(k + 0) * 64 + f];
        acc += zv.y * Wl[(k + 1) * 64 + f];
        acc += zv.z * Wl[(k + 2) * 64 + f];
        acc += zv.w * Wl[(k + 3) * 64 + f];
    }
    int node = node0 + row;
    if (node < N) hs2[(size_t)node * 64 + f] = acc * dinv[node];
}
template <int F>
__global__ void k_agg_init(const float* __restrict__ hs, const float* __restrict__ b,
                           const float* __restrict__ dinv, float* __restrict__ agg, int N)
{
    long long t = (long long)blockIdx.x * blockDim.x + threadIdx.x;
    int n = (int)(t / F), f = (int)(t % F);
    if (n < N) agg[(size_t)n * F + f] = hs[(size_t)n * F + f] * dinv[n] + b[f];
}
template <int F>
__global__ void k_edge_atomic(const int* __restrict__ ei, const float* __restrict__ hs,
                              const float* __restrict__ dinv, float* __restrict__ agg, int E)
{
    long long tid = (long long)blockIdx.x * blockDim.x + threadIdx.x;
    int e = (int)(tid / F), f = (int)(tid % F);
    if (e < E) {
        int s = ei[e], d = ei[E + e];
        atomicAdd(&agg[(size_t)d * F + f], hs[(size_t)s * F + f] * dinv[d]);
    }
}
__global__ __launch_bounds__(256) void k_mlp(
    const float* __restrict__ agg2, const float* __restrict__ Wm1,
    const float* __restrict__ bm1, const float* __restrict__ Wm2,
    const float* __restrict__ bm2, float* __restrict__ vout, int N)
{
    __shared__ float Wl[64 * 64];
    __shared__ float W2l[64];
    __shared__ __align__(16) float Zl[4][64];
    const int tid = threadIdx.x;
    for (int i = tid; i < 64 * 64; i += 256) Wl[i] = Wm1[i];
    if (tid < 64) W2l[tid] = Wm2[tid];
    const int wid = tid >> 6, lane = tid & 63;
    const int node = blockIdx.x * 4 + wid;
    float zv = 0.f;
    if (node < N) zv = fmaxf(agg2[(size_t)node * 64 + lane], 0.f);
    Zl[wid][lane] = zv;
    __syncthreads();
    float t = bm1[lane];
#pragma unroll
    for (int k = 0; k < 64; k += 4) {
        float4 z4 = *(const float4*)&Zl[wid][k];
        t += z4.x * Wl[(k + 0) * 64 + lane];
        t += z4.y * Wl[(k + 1) * 64 + lane];
        t += z4.z * Wl[(k + 2) * 64 + lane];
        t += z4.w * Wl[(k + 3) * 64 + lane];
    }
    t = fmaxf(t, 0.f);
    float val = t * W2l[lane];
#pragma unroll
    for (int off = 32; off > 0; off >>= 1) val += __shfl_down(val, off, 64);
    if (lane == 0 && node < N) vout[node] = val + bm2[0];
}
// ---------------------------------------------------------------------------

extern "C" void kernel_launch(void* const* d_in, const int* in_sizes, int n_in,
                              void* d_out, int out_size, void* d_ws, size_t ws_size,
                              hipStream_t stream)
{
    const float* x   = (const float*)d_in[0];
    const float* W1  = (const float*)d_in[1];
    const float* b1  = (const float*)d_in[2];
    const float* W2  = (const float*)d_in[3];
    const float* b2  = (const float*)d_in[4];
    const float* Wm1 = (const float*)d_in[5];
    const float* bm1 = (const float*)d_in[6];
    const float* Wm2 = (const float*)d_in[7];
    const float* bm2 = (const float*)d_in[8];
    const int*   ei  = (const int*)d_in[9];
    const int*   nn  = (const int*)d_in[10];
    const int N = in_sizes[0] / 128;
    const int E = in_sizes[9] / 2;
    float* out = (float*)d_out;

    const int NB = (N + BKN - 1) / BKN;
    const int nblk = (E + CHUNK - 1) / CHUNK;
    const long long T = (long long)NB * nblk;
    const int nb1 = (int)((T + 255) / 256);
    const size_t need_ints = (size_t)T + (size_t)(T + 1) + 512
                           + (size_t)E /*codes*/ + (size_t)E /*esrc*/
                           + (size_t)(N + 1) /*row_start*/ + (size_t)N /*dinv*/
                           + 96ull * N /*hs1,Zs,Y*/ + (size_t)N /*vtmp*/;
    const bool use_new = (N <= 131072) && (T <= 131072) && (nb1 <= 512)
                       && (ws_size >= need_ints * sizeof(int));

    k_zero_out<<<1, 64, 0, stream>>>(out, out_size);

    if (use_new) {
        int*   table     = (int*)d_ws;                 // T
        int*   S         = table + T;                  // T+1
        int*   bsums     = S + (T + 1);                // 512
        int*   codes     = bsums + 512;                // E
        int*   esrc      = codes + E;                  // E
        int*   row_start = esrc + E;                   // N+1
        float* dinv      = (float*)(row_start + N + 1);// N
        float* hs1       = dinv + N;                   // 32N
        float* Zs        = hs1 + 32 * (size_t)N;       // 32N
        float* Y         = Zs + 32 * (size_t)N;        // 32N
        float* vtmp      = Y + 32 * (size_t)N;         // N

        k_count_coarse<<<nblk, 256, 0, stream>>>(ei + E, table, E, nblk, NB);
        k_scan1<<<nb1, 256, 0, stream>>>(table, S, bsums, (int)T);
        k_scan2<<<1, 512, 0, stream>>>(bsums, nb1);
        k_scan3<<<nb1, 256, 0, stream>>>(S, bsums, (int)T);
        k_scatter2<<<nblk, 256, 0, stream>>>(ei, S, codes, E, nblk, NB);
        k_fine<<<NB, 256, 0, stream>>>(codes, S, esrc, row_start, dinv, nblk, N, E, NB);
        k_gemm1<<<(N + 7) / 8, 256, 0, stream>>>(x, W1, dinv, hs1, N);
        k_agg4<true><<<(N + 31) / 32, 256, 0, stream>>>(row_start, esrc, hs1, b1, dinv, Zs, N);
        k_agg4<false><<<(N + 31) / 32, 256, 0, stream>>>(row_start, esrc, Zs, b1, dinv, Y, N);
        const int tgrid = 1024;
        const int nrounds = (N + tgrid * 16 - 1) / (tgrid * 16);
        k_tail<<<tgrid, 256, 0, stream>>>(Y, W2, b2, Wm1, bm1, Wm2, bm2, vtmp, N, nrounds);
        k_reduce<<<(N + 255) / 256, 256, 0, stream>>>(vtmp, nn, out, N, out_size);
    } else {
        // fallback: atomic scatter path
        const size_t Ns = (size_t)N;
        float* dinv = (float*)d_ws;
        float* B    = dinv + N;
        float* hs1  = B;
        float* agg1 = B + 32 * Ns;
        float* hs2  = B + 64 * Ns;
        float* agg2 = B + 128 * Ns;
        float* vtmp = B;
        int*   deg  = (int*)B;

        const int nb = (N + 255) / 256;
        k_zero_int<<<nb, 256, 0, stream>>>(deg, N);
        k_hist<<<(E + 255) / 256, 256, 0, stream>>>(ei + E, deg, E);
        k_dinv<<<nb, 256, 0, stream>>>(deg, dinv, N);
        k_gemm1<<<(N + 7) / 8, 256, 0, stream>>>(x, W1, dinv, hs1, N);
        {
            long long t = (long long)N * 32;
            k_agg_init<32><<<(unsigned)((t + 255) / 256), 256, 0, stream>>>(hs1, b1, dinv, agg1, N);
            t = (long long)E * 32;
            k_edge_atomic<32><<<(unsigned)((t + 255) / 256), 256, 0, stream>>>(ei, hs1, dinv, agg1, E);
        }
        k_gemm2<<<(N + 3) / 4, 256, 0, stream>>>(agg1, W2, dinv, hs2, N);
        {
            long long t = (long long)N * 64;
            k_agg_init<64><<<(unsigned)((t + 255) / 256), 256, 0, stream>>>(hs2, b2, dinv, agg2, N);
            t = (long long)E * 64;
            k_edge_atomic<64><<<(unsigned)((t + 255) / 256), 256, 0, stream>>>(ei, hs2, dinv, agg2, E);
        }
        k_mlp<<<(N + 3) / 4, 256, 0, stream>>>(agg2, Wm1, bm1, Wm2, bm2, vtmp, N);
        k_reduce<<<nb, 256, 0, stream>>>(vtmp, nn, out, N, out_size);
    }
}

// Round 5
// 352.773 us; speedup vs baseline: 3.7493x; 1.2292x over previous
//
#include <hip/hip_runtime.h>

// ---------------------------------------------------------------------------
// CriticNetwork: 2x GCNConv (relu) + MLP head + per-graph mean.
// Round 5: fp16 storage for gathered feature rows (64 B/row = 1 line/edge,
// halves gather traffic; fp32 accumulate), per-graph mean fused into k_tail,
// int4-vectorized sort-stream reads. CSR build unchanged from round 4.
// ---------------------------------------------------------------------------

typedef _Float16 half_t;
typedef __attribute__((ext_vector_type(8))) _Float16 half8;

#define CHUNK 16384   // edges per sort block
#define BKN   128     // nodes per coarse bucket
#define NBMAX 1024    // max coarse buckets (N <= 131072)

__global__ void k_zero_out(float* out, int n) {
    int i = blockIdx.x * blockDim.x + threadIdx.x;
    if (i < n) out[i] = 0.0f;
}

// ---- coarse counting sort ------------------------------------------------

__global__ __launch_bounds__(256) void k_count_coarse(
    const int* __restrict__ dst, int* __restrict__ table, int E, int nblk, int NB)
{
    __shared__ int cnt[NBMAX];
    const int tid = threadIdx.x;
    for (int i = tid; i < NB; i += 256) cnt[i] = 0;
    __syncthreads();
    const int base = blockIdx.x * CHUNK;
    const int lim = min(CHUNK, E - base);
    if (lim == CHUNK) {
        const int4* d4 = (const int4*)(dst + base);
        for (int i = tid; i < CHUNK / 4; i += 256) {
            int4 v = d4[i];
            atomicAdd(&cnt[v.x >> 7], 1);
            atomicAdd(&cnt[v.y >> 7], 1);
            atomicAdd(&cnt[v.z >> 7], 1);
            atomicAdd(&cnt[v.w >> 7], 1);
        }
    } else {
        for (int i = tid; i < lim; i += 256) atomicAdd(&cnt[dst[base + i] >> 7], 1);
    }
    __syncthreads();
    for (int b = tid; b < NB; b += 256) table[b * nblk + blockIdx.x] = cnt[b];
}

__global__ __launch_bounds__(256) void k_scan1(const int* __restrict__ cnts, int* __restrict__ S,
                                               int* __restrict__ bsums, int T) {
    __shared__ int sh[256];
    int t = threadIdx.x;
    int i = blockIdx.x * 256 + t;
    int v = (i < T) ? cnts[i] : 0;
    sh[t] = v;
    __syncthreads();
    for (int off = 1; off < 256; off <<= 1) {
        int tv = (t >= off) ? sh[t - off] : 0;
        __syncthreads();
        sh[t] += tv;
        __syncthreads();
    }
    if (i < T) S[i + 1] = sh[t];
    if (t == 255) bsums[blockIdx.x] = sh[255];
}

__global__ __launch_bounds__(512) void k_scan2(int* bs, int nb) {
    __shared__ int sh[512];
    int t = threadIdx.x;
    int v = (t < nb) ? bs[t] : 0;
    sh[t] = v;
    __syncthreads();
    for (int off = 1; off < 512; off <<= 1) {
        int tv = (t >= off) ? sh[t - off] : 0;
        __syncthreads();
        sh[t] += tv;
        __syncthreads();
    }
    if (t < nb) bs[t] = sh[t] - v;  // exclusive
}

__global__ void k_scan3(int* __restrict__ S, const int* __restrict__ bs, int T) {
    int i = blockIdx.x * blockDim.x + threadIdx.x;
    if (i < T) S[i + 1] += bs[i >> 8];
    if (i == 0) S[0] = 0;
}

__global__ __launch_bounds__(256) void k_scatter2(
    const int* __restrict__ ei, const int* __restrict__ S,
    int* __restrict__ codes, int E, int nblk, int NB)
{
    __shared__ int cur[NBMAX];
    const int tid = threadIdx.x;
    for (int i = tid; i < NB; i += 256) cur[i] = 0;
    __syncthreads();
    const int base = blockIdx.x * CHUNK;
    const int lim = min(CHUNK, E - base);
    const int* Sc = S + (size_t)0;
    if (lim == CHUNK) {
        const int4* s4 = (const int4*)(ei + base);
        const int4* d4 = (const int4*)(ei + E + base);
        for (int i = tid; i < CHUNK / 4; i += 256) {
            int4 sv = s4[i], dv = d4[i];
            {
                int b = dv.x >> 7; int r = atomicAdd(&cur[b], 1);
                codes[Sc[b * nblk + blockIdx.x] + r] = ((dv.x & 127) << 17) | sv.x;
            }
            {
                int b = dv.y >> 7; int r = atomicAdd(&cur[b], 1);
                codes[Sc[b * nblk + blockIdx.x] + r] = ((dv.y & 127) << 17) | sv.y;
            }
            {
                int b = dv.z >> 7; int r = atomicAdd(&cur[b], 1);
                codes[Sc[b * nblk + blockIdx.x] + r] = ((dv.z & 127) << 17) | sv.z;
            }
            {
                int b = dv.w >> 7; int r = atomicAdd(&cur[b], 1);
                codes[Sc[b * nblk + blockIdx.x] + r] = ((dv.w & 127) << 17) | sv.w;
            }
        }
    } else {
        for (int i = tid; i < lim; i += 256) {
            int e = base + i;
            int s = ei[e], d = ei[E + e];
            int b = d >> 7;
            int r = atomicAdd(&cur[b], 1);
            codes[Sc[b * nblk + blockIdx.x] + r] = ((d & 127) << 17) | s;
        }
    }
}

// per-bucket fine CSR: degree count -> LDS scan -> dst-sorted esrc + row_start + dinv
__global__ __launch_bounds__(256) void k_fine(
    const int* __restrict__ codes, const int* __restrict__ S,
    int* __restrict__ esrc, int* __restrict__ row_start,
    float* __restrict__ dinv, int nblk, int N, int E, int NB)
{
    __shared__ int cnt[BKN];
    __shared__ int sh[BKN];
    __shared__ int cur[BKN];
    const int tid = threadIdx.x;
    if (tid < BKN) cnt[tid] = 0;
    __syncthreads();
    const int b = blockIdx.x;
    const int beg = S[b * nblk], end = S[(b + 1) * nblk];
    for (int e = beg + tid; e < end; e += 256) atomicAdd(&cnt[codes[e] >> 17], 1);
    __syncthreads();
    if (tid < BKN) sh[tid] = cnt[tid];
    __syncthreads();
    for (int off = 1; off < BKN; off <<= 1) {
        int tv = (tid >= off && tid < BKN) ? sh[tid - off] : 0;
        __syncthreads();
        if (tid < BKN) sh[tid] += tv;
        __syncthreads();
    }
    if (tid < BKN) {
        int fs = beg + sh[tid] - cnt[tid];   // exclusive prefix, global offset
        cur[tid] = fs;
        int n = b * BKN + tid;
        if (n < N) {
            row_start[n] = fs;
            dinv[n] = rsqrtf(1.0f + (float)cnt[tid]);
        }
    }
    if (b == NB - 1 && tid == 0) row_start[N] = E;
    __syncthreads();
    for (int e = beg + tid; e < end; e += 256) {
        int c = codes[e];
        int pos = atomicAdd(&cur[c >> 17], 1);
        esrc[pos] = c & 0x1FFFF;
    }
}

// ---- dense compute -------------------------------------------------------

// hs1 = fp16( (x @ W1) * dinv )   (N x 128 @ 128 x 32)
__global__ __launch_bounds__(256) void k_gemm1(
    const float* __restrict__ x, const float* __restrict__ W,
    const float* __restrict__ dinv, half_t* __restrict__ hs1, int N)
{
    __shared__ float Wl[128 * 32];
    __shared__ __align__(16) float Xl[8 * 132];
    const int tid = threadIdx.x;
    for (int i = tid; i < 128 * 32; i += 256) Wl[i] = W[i];
    const int node0 = blockIdx.x * 8;
    {
        int r = tid >> 5, c4 = tid & 31;
        int node = node0 + r;
        float4 v = make_float4(0.f, 0.f, 0.f, 0.f);
        if (node < N) v = ((const float4*)(x + (size_t)node * 128))[c4];
        *(float4*)&Xl[r * 132 + c4 * 4] = v;
    }
    __syncthreads();
    const int row = tid >> 5, f = tid & 31;
    float acc = 0.f;
#pragma unroll
    for (int k = 0; k < 128; k += 4) {
        float4 xv = *(const float4*)&Xl[row * 132 + k];
        acc += xv.x * Wl[(k + 0) * 32 + f];
        acc += xv.y * Wl[(k + 1) * 32 + f];
        acc += xv.z * Wl[(k + 2) * 32 + f];
        acc += xv.w * Wl[(k + 3) * 32 + f];
    }
    const int node = node0 + row;
    if (node < N) hs1[(size_t)node * 32 + f] = (half_t)(acc * dinv[node]);
}

// node-parallel fp16 CSR gather-reduce. 4 lanes/node (16 B each = one 64 B
// line per edge), 64 nodes/block, fp32 accumulate.
// L1: OUT = fp16( relu(dinv*(IN[self]+sum) + bias) * dinv )
// L2: OUT = fp16( dinv*(IN[self]+sum) )
template <bool L1>
__global__ __launch_bounds__(256) void k_aggh(
    const int* __restrict__ row_start, const int* __restrict__ esrc,
    const half_t* __restrict__ IN, const float* __restrict__ bias,
    const float* __restrict__ dinv, half_t* __restrict__ OUT, int N)
{
    const int tid = threadIdx.x;
    const int g = tid >> 2, l = tid & 3;       // 64 nodes x 4 lanes
    const int n = blockIdx.x * 64 + g;
    if (n >= N) return;
    const half8* IN8 = (const half8*)IN;       // row = 4 x half8
    const int beg = row_start[n], end = row_start[n + 1];
    half8 self = IN8[(size_t)n * 4 + l];
    float acc[8];
#pragma unroll
    for (int j = 0; j < 8; ++j) acc[j] = (float)self[j];
    int e = beg;
    for (; e + 3 < end; e += 4) {
        int s0 = esrc[e], s1 = esrc[e + 1], s2 = esrc[e + 2], s3 = esrc[e + 3];
        half8 v0 = IN8[(size_t)s0 * 4 + l];
        half8 v1 = IN8[(size_t)s1 * 4 + l];
        half8 v2 = IN8[(size_t)s2 * 4 + l];
        half8 v3 = IN8[(size_t)s3 * 4 + l];
#pragma unroll
        for (int j = 0; j < 8; ++j)
            acc[j] += ((float)v0[j] + (float)v1[j]) + ((float)v2[j] + (float)v3[j]);
    }
    for (; e < end; ++e) {
        half8 v = IN8[(size_t)esrc[e] * 4 + l];
#pragma unroll
        for (int j = 0; j < 8; ++j) acc[j] += (float)v[j];
    }
    const float dv = dinv[n];
    half8 o;
    if (L1) {
#pragma unroll
        for (int j = 0; j < 8; ++j) {
            float bb = bias[l * 8 + j];
            o[j] = (half_t)(fmaxf(dv * acc[j] + bb, 0.f) * dv);
        }
    } else {
#pragma unroll
        for (int j = 0; j < 8; ++j) o[j] = (half_t)(dv * acc[j]);
    }
    ((half8*)OUT)[(size_t)n * 4 + l] = o;
}

// fused tail + per-graph mean: per node v = relu(relu(Y@W2+b2)@Wm1+bm1)@Wm2+bm2;
// block-local partial sums per graph -> one atomicAdd per (block, graph).
__global__ __launch_bounds__(256) void k_tail(
    const half_t* __restrict__ Y, const float* __restrict__ W2, const float* __restrict__ b2,
    const float* __restrict__ Wm1, const float* __restrict__ bm1,
    const float* __restrict__ Wm2, const float* __restrict__ bm2,
    const int* __restrict__ num_nodes_p, float* __restrict__ out,
    int N, int n_graphs, int nrounds)
{
    __shared__ float W2l[32 * 64];
    __shared__ float W1l[64 * 64];
    __shared__ float b2l[64], bm1l[64], w2v[64];
    __shared__ float gacc[32];
    __shared__ __align__(16) float ybuf[4][4][32];
    __shared__ __align__(16) float zbuf[4][4][64];
    const int tid = threadIdx.x;
    for (int i = tid; i < 32 * 64; i += 256) W2l[i] = W2[i];
    for (int i = tid; i < 64 * 64; i += 256) W1l[i] = Wm1[i];
    if (tid < 64) { b2l[tid] = b2[tid]; bm1l[tid] = bm1[tid]; w2v[tid] = Wm2[tid]; }
    if (tid < 32) gacc[tid] = 0.f;
    __syncthreads();
    const int wid = tid >> 6, lane = tid & 63;
    const float bm2v = bm2[0];
    const int nnv = num_nodes_p[0];
    const half8* Y8 = (const half8*)Y;
    for (int r = 0; r < nrounds; ++r) {
        const int base = (blockIdx.x + r * gridDim.x) * 16 + wid * 4;
        if (lane < 16) {
            int nd = lane >> 2, l = lane & 3, n = base + nd;
            half8 v = (half8)(_Float16)0;
            if (n < N) v = Y8[(size_t)n * 4 + l];
#pragma unroll
            for (int j = 0; j < 8; ++j) ybuf[wid][nd][l * 8 + j] = (float)v[j];
        }
        float h0 = b2l[lane], h1 = h0, h2 = h0, h3 = h0;
#pragma unroll
        for (int k = 0; k < 32; k += 4) {
            float w0 = W2l[(k + 0) * 64 + lane], w1 = W2l[(k + 1) * 64 + lane];
            float w2 = W2l[(k + 2) * 64 + lane], w3 = W2l[(k + 3) * 64 + lane];
            float4 ya = *(const float4*)&ybuf[wid][0][k];
            float4 yb = *(const float4*)&ybuf[wid][1][k];
            float4 yc = *(const float4*)&ybuf[wid][2][k];
            float4 yd = *(const float4*)&ybuf[wid][3][k];
            h0 += ya.x * w0 + ya.y * w1 + ya.z * w2 + ya.w * w3;
            h1 += yb.x * w0 + yb.y * w1 + yb.z * w2 + yb.w * w3;
            h2 += yc.x * w0 + yc.y * w1 + yc.z * w2 + yc.w * w3;
            h3 += yd.x * w0 + yd.y * w1 + yd.z * w2 + yd.w * w3;
        }
        zbuf[wid][0][lane] = fmaxf(h0, 0.f);
        zbuf[wid][1][lane] = fmaxf(h1, 0.f);
        zbuf[wid][2][lane] = fmaxf(h2, 0.f);
        zbuf[wid][3][lane] = fmaxf(h3, 0.f);
        float t0 = bm1l[lane], t1 = t0, t2 = t0, t3 = t0;
#pragma unroll
        for (int k = 0; k < 64; k += 4) {
            float w0 = W1l[(k + 0) * 64 + lane], w1 = W1l[(k + 1) * 64 + lane];
            float w2 = W1l[(k + 2) * 64 + lane], w3 = W1l[(k + 3) * 64 + lane];
            float4 za = *(const float4*)&zbuf[wid][0][k];
            float4 zb = *(const float4*)&zbuf[wid][1][k];
            float4 zc = *(const float4*)&zbuf[wid][2][k];
            float4 zd = *(const float4*)&zbuf[wid][3][k];
            t0 += za.x * w0 + za.y * w1 + za.z * w2 + za.w * w3;
            t1 += zb.x * w0 + zb.y * w1 + zb.z * w2 + zb.w * w3;
            t2 += zc.x * w0 + zc.y * w1 + zc.z * w2 + zc.w * w3;
            t3 += zd.x * w0 + zd.y * w1 + zd.z * w2 + zd.w * w3;
        }
        float v0 = fmaxf(t0, 0.f) * w2v[lane];
        float v1 = fmaxf(t1, 0.f) * w2v[lane];
        float v2 = fmaxf(t2, 0.f) * w2v[lane];
        float v3 = fmaxf(t3, 0.f) * w2v[lane];
#pragma unroll
        for (int off = 32; off > 0; off >>= 1) {
            v0 += __shfl_down(v0, off, 64);
            v1 += __shfl_down(v1, off, 64);
            v2 += __shfl_down(v2, off, 64);
            v3 += __shfl_down(v3, off, 64);
        }
        if (lane == 0) {
            float vv[4] = {v0, v1, v2, v3};
            for (int i = 0; i < 4; ++i) {
                int n = base + i;
                if (n < N) {
                    int gg = n / nnv;
                    if (gg < 32) atomicAdd(&gacc[gg], vv[i] + bm2v);
                }
            }
        }
    }
    __syncthreads();
    if (tid < n_graphs && tid < 32) atomicAdd(&out[tid], gacc[tid] / (float)nnv);
}

// ---- fallback (atomic) path ----------------------------------------------
__global__ void k_zero_int(int* p, int n) {
    int i = blockIdx.x * blockDim.x + threadIdx.x;
    if (i < n) p[i] = 0;
}
__global__ void k_hist(const int* __restrict__ dst, int* __restrict__ deg, int E) {
    int e = blockIdx.x * blockDim.x + threadIdx.x;
    if (e < E) atomicAdd(&deg[dst[e]], 1);
}
__global__ void k_dinv(const int* __restrict__ deg, float* __restrict__ dinv, int n) {
    int i = blockIdx.x * blockDim.x + threadIdx.x;
    if (i < n) dinv[i] = rsqrtf(1.0f + (float)deg[i]);
}
__global__ __launch_bounds__(256) void k_gemm1f(
    const float* __restrict__ x, const float* __restrict__ W,
    const float* __restrict__ dinv, float* __restrict__ hs1, int N)
{
    __shared__ float Wl[128 * 32];
    __shared__ __align__(16) float Xl[8 * 132];
    const int tid = threadIdx.x;
    for (int i = tid; i < 128 * 32; i += 256) Wl[i] = W[i];
    const int node0 = blockIdx.x * 8;
    {
        int r = tid >> 5, c4 = tid & 31;
        int node = node0 + r;
        float4 v = make_float4(0.f, 0.f, 0.f, 0.f);
        if (node < N) v = ((const float4*)(x + (size_t)node * 128))[c4];
        *(float4*)&Xl[r * 132 + c4 * 4] = v;
    }
    __syncthreads();
    const int row = tid >> 5, f = tid & 31;
    float acc = 0.f;
#pragma unroll
    for (int k = 0; k < 128; k += 4) {
        float4 xv = *(const float4*)&Xl[row * 132 + k];
        acc += xv.x * Wl[(k + 0) * 32 + f];
        acc += xv.y * Wl[(k + 1) * 32 + f];
        acc += xv.z * Wl[(k + 2) * 32 + f];
        acc += xv.w * Wl[(k + 3) * 32 + f];
    }
    const int node = node0 + row;
    if (node < N) hs1[(size_t)node * 32 + f] = acc * dinv[node];
}
__global__ __launch_bounds__(256) void k_gemm2(
    const float* __restrict__ agg1, const float* __restrict__ W,
    const float* __restrict__ dinv, float* __restrict__ hs2, int N)
{
    __shared__ float Wl[32 * 64];
    __shared__ __align__(16) float Zl[4 * 36];
    const int tid = threadIdx.x;
    for (int i = tid; i < 32 * 64; i += 256) Wl[i] = W[i];
    const int node0 = blockIdx.x * 4;
    if (tid < 128) {
        int r = tid >> 5, c = tid & 31;
        int node = node0 + r;
        float v = 0.f;
        if (node < N) v = fmaxf(agg1[(size_t)node * 32 + c], 0.f);
        Zl[r * 36 + c] = v;
    }
    __syncthreads();
    const int row = tid >> 6, f = tid & 63;
    float acc = 0.f;
#pragma unroll
    for (int k = 0; k < 32; k += 4) {
        float4 zv = *(const float4*)&Zl[row * 36 + k];
        acc += zv.x * Wl[(k + 0) * 64 + f];
        acc += zv.y * Wl[(k + 1) * 64 + f];
        acc += zv.z * Wl[(k + 2) * 64 + f];
        acc += zv.w * Wl[(k + 3) * 64 + f];
    }
    int node = node0 + row;
    if (node < N) hs2[(size_t)node * 64 + f] = acc * dinv[node];
}
template <int F>
__global__ void k_agg_init(const float* __restrict__ hs, const float* __restrict__ b,
                           const float* __restrict__ dinv, float* __restrict__ agg, int N)
{
    long long t = (long long)blockIdx.x * blockDim.x + threadIdx.x;
    int n = (int)(t / F), f = (int)(t % F);
    if (n < N) agg[(size_t)n * F + f] = hs[(size_t)n * F + f] * dinv[n] + b[f];
}
template <int F>
__global__ void k_edge_atomic(const int* __restrict__ ei, const float* __restrict__ hs,
                              const float* __restrict__ dinv, float* __restrict__ agg, int E)
{
    long long tid = (long long)blockIdx.x * blockDim.x + threadIdx.x;
    int e = (int)(tid / F), f = (int)(tid % F);
    if (e < E) {
        int s = ei[e], d = ei[E + e];
        atomicAdd(&agg[(size_t)d * F + f], hs[(size_t)s * F + f] * dinv[d]);
    }
}
__global__ __launch_bounds__(256) void k_mlp(
    const float* __restrict__ agg2, const float* __restrict__ Wm1,
    const float* __restrict__ bm1, const float* __restrict__ Wm2,
    const float* __restrict__ bm2, float* __restrict__ vout, int N)
{
    __shared__ float Wl[64 * 64];
    __shared__ float W2l[64];
    __shared__ __align__(16) float Zl[4][64];
    const int tid = threadIdx.x;
    for (int i = tid; i < 64 * 64; i += 256) Wl[i] = Wm1[i];
    if (tid < 64) W2l[tid] = Wm2[tid];
    const int wid = tid >> 6, lane = tid & 63;
    const int node = blockIdx.x * 4 + wid;
    float zv = 0.f;
    if (node < N) zv = fmaxf(agg2[(size_t)node * 64 + lane], 0.f);
    Zl[wid][lane] = zv;
    __syncthreads();
    float t = bm1[lane];
#pragma unroll
    for (int k = 0; k < 64; k += 4) {
        float4 z4 = *(const float4*)&Zl[wid][k];
        t += z4.x * Wl[(k + 0) * 64 + lane];
        t += z4.y * Wl[(k + 1) * 64 + lane];
        t += z4.z * Wl[(k + 2) * 64 + lane];
        t += z4.w * Wl[(k + 3) * 64 + lane];
    }
    t = fmaxf(t, 0.f);
    float val = t * W2l[lane];
#pragma unroll
    for (int off = 32; off > 0; off >>= 1) val += __shfl_down(val, off, 64);
    if (lane == 0 && node < N) vout[node] = val + bm2[0];
}
__global__ void k_reduce(const float* __restrict__ v, const int* __restrict__ num_nodes_p,
                         float* out, int N, int n_graphs)
{
    __shared__ float acc[32];
    int tid = threadIdx.x;
    if (tid < n_graphs) acc[tid] = 0.f;
    __syncthreads();
    int i = blockIdx.x * blockDim.x + tid;
    int nn = num_nodes_p[0];
    if (i < N) {
        int g = i / nn;
        if (g < n_graphs) atomicAdd(&acc[g], v[i]);
    }
    __syncthreads();
    if (tid < n_graphs) atomicAdd(&out[tid], acc[tid] / (float)nn);
}
// ---------------------------------------------------------------------------

extern "C" void kernel_launch(void* const* d_in, const int* in_sizes, int n_in,
                              void* d_out, int out_size, void* d_ws, size_t ws_size,
                              hipStream_t stream)
{
    const float* x   = (const float*)d_in[0];
    const float* W1  = (const float*)d_in[1];
    const float* b1  = (const float*)d_in[2];
    const float* W2  = (const float*)d_in[3];
    const float* b2  = (const float*)d_in[4];
    const float* Wm1 = (const float*)d_in[5];
    const float* bm1 = (const float*)d_in[6];
    const float* Wm2 = (const float*)d_in[7];
    const float* bm2 = (const float*)d_in[8];
    const int*   ei  = (const int*)d_in[9];
    const int*   nn  = (const int*)d_in[10];
    const int N = in_sizes[0] / 128;
    const int E = in_sizes[9] / 2;
    float* out = (float*)d_out;

    const int NB = (N + BKN - 1) / BKN;
    const int nblk = (E + CHUNK - 1) / CHUNK;
    const long long T = (long long)NB * nblk;
    const int nb1 = (int)((T + 255) / 256);
    // ints: table T + S (T+1) + bsums 512 + codes E + esrc E + row_start N+1
    //     + dinv N + hs1h 16N + Zs 16N + Y 16N
    const size_t need_ints = (size_t)T + (size_t)(T + 1) + 512
                           + (size_t)E + (size_t)E + (size_t)(N + 1)
                           + (size_t)N + 48ull * N;
    const bool use_new = (N <= 131072) && (T <= 131072) && (nb1 <= 512)
                       && (out_size <= 32)
                       && (ws_size >= need_ints * sizeof(int));

    k_zero_out<<<1, 64, 0, stream>>>(out, out_size);

    if (use_new) {
        int*    table     = (int*)d_ws;                  // T
        int*    S         = table + T;                   // T+1
        int*    bsums     = S + (T + 1);                 // 512
        int*    codes     = bsums + 512;                 // E
        int*    esrc      = codes + E;                   // E
        int*    row_start = esrc + E;                    // N+1
        float*  dinv      = (float*)(row_start + N + 1); // N
        half_t* hs1h      = (half_t*)(dinv + N);         // 32N halves (16N ints)
        half_t* Zs        = hs1h + 32 * (size_t)N;       // 32N halves
        half_t* Y         = Zs + 32 * (size_t)N;         // 32N halves

        k_count_coarse<<<nblk, 256, 0, stream>>>(ei + E, table, E, nblk, NB);
        k_scan1<<<nb1, 256, 0, stream>>>(table, S, bsums, (int)T);
        k_scan2<<<1, 512, 0, stream>>>(bsums, nb1);
        k_scan3<<<nb1, 256, 0, stream>>>(S, bsums, (int)T);
        k_scatter2<<<nblk, 256, 0, stream>>>(ei, S, codes, E, nblk, NB);
        k_fine<<<NB, 256, 0, stream>>>(codes, S, esrc, row_start, dinv, nblk, N, E, NB);
        k_gemm1<<<(N + 7) / 8, 256, 0, stream>>>(x, W1, dinv, hs1h, N);
        k_aggh<true><<<(N + 63) / 64, 256, 0, stream>>>(row_start, esrc, hs1h, b1, dinv, Zs, N);
        k_aggh<false><<<(N + 63) / 64, 256, 0, stream>>>(row_start, esrc, Zs, b1, dinv, Y, N);
        const int tgrid = 1024;
        const int nrounds = (N + tgrid * 16 - 1) / (tgrid * 16);
        k_tail<<<tgrid, 256, 0, stream>>>(Y, W2, b2, Wm1, bm1, Wm2, bm2, nn, out,
                                          N, out_size, nrounds);
    } else {
        // fallback: fp32 atomic scatter path
        const size_t Ns = (size_t)N;
        float* dinv = (float*)d_ws;
        float* B    = dinv + N;
        float* hs1  = B;
        float* agg1 = B + 32 * Ns;
        float* hs2  = B + 64 * Ns;
        float* agg2 = B + 128 * Ns;
        float* vtmp = B;
        int*   deg  = (int*)B;

        const int nb = (N + 255) / 256;
        k_zero_int<<<nb, 256, 0, stream>>>(deg, N);
        k_hist<<<(E + 255) / 256, 256, 0, stream>>>(ei + E, deg, E);
        k_dinv<<<nb, 256, 0, stream>>>(deg, dinv, N);
        k_gemm1f<<<(N + 7) / 8, 256, 0, stream>>>(x, W1, dinv, hs1, N);
        {
            long long t = (long long)N * 32;
            k_agg_init<32><<<(unsigned)((t + 255) / 256), 256, 0, stream>>>(hs1, b1, dinv, agg1, N);
            t = (long long)E * 32;
            k_edge_atomic<32><<<(unsigned)((t + 255) / 256), 256, 0, stream>>>(ei, hs1, dinv, agg1, E);
        }
        k_gemm2<<<(N + 3) / 4, 256, 0, stream>>>(agg1, W2, dinv, hs2, N);
        {
            long long t = (long long)N * 64;
            k_agg_init<64><<<(unsigned)((t + 255) / 256), 256, 0, stream>>>(hs2, b2, dinv, agg2, N);
            t = (long long)E * 64;
            k_edge_atomic<64><<<(unsigned)((t + 255) / 256), 256, 0, stream>>>(ei, hs2, dinv, agg2, E);
        }
        k_mlp<<<(N + 3) / 4, 256, 0, stream>>>(agg2, Wm1, bm1, Wm2, bm2, vtmp, N);
        k_reduce<<<nb, 256, 0, stream>>>(vtmp, nn, out, N, out_size);
    }
}

// Round 6
// 330.864 us; speedup vs baseline: 3.9976x; 1.0662x over previous
//
#include <hip/hip_runtime.h>

// ---------------------------------------------------------------------------
// CriticNetwork: 2x GCNConv (relu) + MLP head + per-graph mean.
// Round 6: MFMA tail (fp16 16x16x32, A-frag direct from fp16 Y; H transposed
// through wave-private padded LDS; per-graph mean fused), CHUNK 16384->8192
// for 2x sort parallelism. CSR build + fp16 gather path otherwise unchanged.
// ---------------------------------------------------------------------------

typedef _Float16 half_t;
typedef __attribute__((ext_vector_type(8))) _Float16 half8;
typedef __attribute__((ext_vector_type(4))) float f32x4;

#define CHUNK 8192    // edges per sort block
#define BKN   128     // nodes per coarse bucket
#define NBMAX 1024    // max coarse buckets (N <= 131072)

__global__ void k_zero_out(float* out, int n) {
    int i = blockIdx.x * blockDim.x + threadIdx.x;
    if (i < n) out[i] = 0.0f;
}

// ---- coarse counting sort ------------------------------------------------

__global__ __launch_bounds__(256) void k_count_coarse(
    const int* __restrict__ dst, int* __restrict__ table, int E, int nblk, int NB)
{
    __shared__ int cnt[NBMAX];
    const int tid = threadIdx.x;
    for (int i = tid; i < NB; i += 256) cnt[i] = 0;
    __syncthreads();
    const int base = blockIdx.x * CHUNK;
    const int lim = min(CHUNK, E - base);
    if (lim == CHUNK) {
        const int4* d4 = (const int4*)(dst + base);
        for (int i = tid; i < CHUNK / 4; i += 256) {
            int4 v = d4[i];
            atomicAdd(&cnt[v.x >> 7], 1);
            atomicAdd(&cnt[v.y >> 7], 1);
            atomicAdd(&cnt[v.z >> 7], 1);
            atomicAdd(&cnt[v.w >> 7], 1);
        }
    } else {
        for (int i = tid; i < lim; i += 256) atomicAdd(&cnt[dst[base + i] >> 7], 1);
    }
    __syncthreads();
    for (int b = tid; b < NB; b += 256) table[b * nblk + blockIdx.x] = cnt[b];
}

__global__ __launch_bounds__(256) void k_scan1(const int* __restrict__ cnts, int* __restrict__ S,
                                               int* __restrict__ bsums, int T) {
    __shared__ int sh[256];
    int t = threadIdx.x;
    int i = blockIdx.x * 256 + t;
    int v = (i < T) ? cnts[i] : 0;
    sh[t] = v;
    __syncthreads();
    for (int off = 1; off < 256; off <<= 1) {
        int tv = (t >= off) ? sh[t - off] : 0;
        __syncthreads();
        sh[t] += tv;
        __syncthreads();
    }
    if (i < T) S[i + 1] = sh[t];
    if (t == 255) bsums[blockIdx.x] = sh[255];
}

// exclusive scan of up to 1024 block sums
__global__ __launch_bounds__(1024) void k_scan2(int* bs, int nb) {
    __shared__ int sh[1024];
    int t = threadIdx.x;
    int v = (t < nb) ? bs[t] : 0;
    sh[t] = v;
    __syncthreads();
    for (int off = 1; off < 1024; off <<= 1) {
        int tv = (t >= off) ? sh[t - off] : 0;
        __syncthreads();
        sh[t] += tv;
        __syncthreads();
    }
    if (t < nb) bs[t] = sh[t] - v;  // exclusive
}

__global__ void k_scan3(int* __restrict__ S, const int* __restrict__ bs, int T) {
    int i = blockIdx.x * blockDim.x + threadIdx.x;
    if (i < T) S[i + 1] += bs[i >> 8];
    if (i == 0) S[0] = 0;
}

__global__ __launch_bounds__(256) void k_scatter2(
    const int* __restrict__ ei, const int* __restrict__ S,
    int* __restrict__ codes, int E, int nblk, int NB)
{
    __shared__ int cur[NBMAX];
    const int tid = threadIdx.x;
    for (int i = tid; i < NB; i += 256) cur[i] = 0;
    __syncthreads();
    const int base = blockIdx.x * CHUNK;
    const int lim = min(CHUNK, E - base);
    if (lim == CHUNK) {
        const int4* s4 = (const int4*)(ei + base);
        const int4* d4 = (const int4*)(ei + E + base);
        for (int i = tid; i < CHUNK / 4; i += 256) {
            int4 sv = s4[i], dv = d4[i];
            {
                int b = dv.x >> 7; int r = atomicAdd(&cur[b], 1);
                codes[S[b * nblk + blockIdx.x] + r] = ((dv.x & 127) << 17) | sv.x;
            }
            {
                int b = dv.y >> 7; int r = atomicAdd(&cur[b], 1);
                codes[S[b * nblk + blockIdx.x] + r] = ((dv.y & 127) << 17) | sv.y;
            }
            {
                int b = dv.z >> 7; int r = atomicAdd(&cur[b], 1);
                codes[S[b * nblk + blockIdx.x] + r] = ((dv.z & 127) << 17) | sv.z;
            }
            {
                int b = dv.w >> 7; int r = atomicAdd(&cur[b], 1);
                codes[S[b * nblk + blockIdx.x] + r] = ((dv.w & 127) << 17) | sv.w;
            }
        }
    } else {
        for (int i = tid; i < lim; i += 256) {
            int e = base + i;
            int s = ei[e], d = ei[E + e];
            int b = d >> 7;
            int r = atomicAdd(&cur[b], 1);
            codes[S[b * nblk + blockIdx.x] + r] = ((d & 127) << 17) | s;
        }
    }
}

// per-bucket fine CSR: degree count -> LDS scan -> dst-sorted esrc + row_start + dinv
__global__ __launch_bounds__(256) void k_fine(
    const int* __restrict__ codes, const int* __restrict__ S,
    int* __restrict__ esrc, int* __restrict__ row_start,
    float* __restrict__ dinv, int nblk, int N, int E, int NB)
{
    __shared__ int cnt[BKN];
    __shared__ int sh[BKN];
    __shared__ int cur[BKN];
    const int tid = threadIdx.x;
    if (tid < BKN) cnt[tid] = 0;
    __syncthreads();
    const int b = blockIdx.x;
    const int beg = S[b * nblk], end = S[(b + 1) * nblk];
    for (int e = beg + tid; e < end; e += 256) atomicAdd(&cnt[codes[e] >> 17], 1);
    __syncthreads();
    if (tid < BKN) sh[tid] = cnt[tid];
    __syncthreads();
    for (int off = 1; off < BKN; off <<= 1) {
        int tv = (tid >= off && tid < BKN) ? sh[tid - off] : 0;
        __syncthreads();
        if (tid < BKN) sh[tid] += tv;
        __syncthreads();
    }
    if (tid < BKN) {
        int fs = beg + sh[tid] - cnt[tid];   // exclusive prefix, global offset
        cur[tid] = fs;
        int n = b * BKN + tid;
        if (n < N) {
            row_start[n] = fs;
            dinv[n] = rsqrtf(1.0f + (float)cnt[tid]);
        }
    }
    if (b == NB - 1 && tid == 0) row_start[N] = E;
    __syncthreads();
    for (int e = beg + tid; e < end; e += 256) {
        int c = codes[e];
        int pos = atomicAdd(&cur[c >> 17], 1);
        esrc[pos] = c & 0x1FFFF;
    }
}

// ---- dense compute -------------------------------------------------------

// hs1 = fp16( (x @ W1) * dinv )   (N x 128 @ 128 x 32)
__global__ __launch_bounds__(256) void k_gemm1(
    const float* __restrict__ x, const float* __restrict__ W,
    const float* __restrict__ dinv, half_t* __restrict__ hs1, int N)
{
    __shared__ float Wl[128 * 32];
    __shared__ __align__(16) float Xl[8 * 132];
    const int tid = threadIdx.x;
    for (int i = tid; i < 128 * 32; i += 256) Wl[i] = W[i];
    const int node0 = blockIdx.x * 8;
    {
        int r = tid >> 5, c4 = tid & 31;
        int node = node0 + r;
        float4 v = make_float4(0.f, 0.f, 0.f, 0.f);
        if (node < N) v = ((const float4*)(x + (size_t)node * 128))[c4];
        *(float4*)&Xl[r * 132 + c4 * 4] = v;
    }
    __syncthreads();
    const int row = tid >> 5, f = tid & 31;
    float acc = 0.f;
#pragma unroll
    for (int k = 0; k < 128; k += 4) {
        float4 xv = *(const float4*)&Xl[row * 132 + k];
        acc += xv.x * Wl[(k + 0) * 32 + f];
        acc += xv.y * Wl[(k + 1) * 32 + f];
        acc += xv.z * Wl[(k + 2) * 32 + f];
        acc += xv.w * Wl[(k + 3) * 32 + f];
    }
    const int node = node0 + row;
    if (node < N) hs1[(size_t)node * 32 + f] = (half_t)(acc * dinv[node]);
}

// node-parallel fp16 CSR gather-reduce (round 5, unchanged)
template <bool L1>
__global__ __launch_bounds__(256) void k_aggh(
    const int* __restrict__ row_start, const int* __restrict__ esrc,
    const half_t* __restrict__ IN, const float* __restrict__ bias,
    const float* __restrict__ dinv, half_t* __restrict__ OUT, int N)
{
    const int tid = threadIdx.x;
    const int g = tid >> 2, l = tid & 3;       // 64 nodes x 4 lanes
    const int n = blockIdx.x * 64 + g;
    if (n >= N) return;
    const half8* IN8 = (const half8*)IN;       // row = 4 x half8
    const int beg = row_start[n], end = row_start[n + 1];
    half8 self = IN8[(size_t)n * 4 + l];
    float acc[8];
#pragma unroll
    for (int j = 0; j < 8; ++j) acc[j] = (float)self[j];
    int e = beg;
    for (; e + 3 < end; e += 4) {
        int s0 = esrc[e], s1 = esrc[e + 1], s2 = esrc[e + 2], s3 = esrc[e + 3];
        half8 v0 = IN8[(size_t)s0 * 4 + l];
        half8 v1 = IN8[(size_t)s1 * 4 + l];
        half8 v2 = IN8[(size_t)s2 * 4 + l];
        half8 v3 = IN8[(size_t)s3 * 4 + l];
#pragma unroll
        for (int j = 0; j < 8; ++j)
            acc[j] += ((float)v0[j] + (float)v1[j]) + ((float)v2[j] + (float)v3[j]);
    }
    for (; e < end; ++e) {
        half8 v = IN8[(size_t)esrc[e] * 4 + l];
#pragma unroll
        for (int j = 0; j < 8; ++j) acc[j] += (float)v[j];
    }
    const float dv = dinv[n];
    half8 o;
    if (L1) {
#pragma unroll
        for (int j = 0; j < 8; ++j) {
            float bb = bias[l * 8 + j];
            o[j] = (half_t)(fmaxf(dv * acc[j] + bb, 0.f) * dv);
        }
    } else {
#pragma unroll
        for (int j = 0; j < 8; ++j) o[j] = (half_t)(dv * acc[j]);
    }
    ((half8*)OUT)[(size_t)n * 4 + l] = o;
}

// transpose+convert weights to fp16: W2t[64][32] from W2[32][64]; Wm1t[64][64]
__global__ __launch_bounds__(256) void k_prep(
    const float* __restrict__ W2, const float* __restrict__ Wm1,
    half_t* __restrict__ W2t, half_t* __restrict__ Wm1t)
{
    int i = blockIdx.x * 256 + threadIdx.x;
    if (i < 32 * 64) { int k = i >> 6, c = i & 63; W2t[c * 32 + k] = (half_t)W2[i]; }
    if (i < 64 * 64) { int k = i >> 6, c = i & 63; Wm1t[c * 64 + k] = (half_t)Wm1[i]; }
}

// MFMA tail: per wave 16 nodes.
//  H = relu(Y@W2 + b2)  via 4x mfma_f32_16x16x32_f16 (K=32)
//  T = H@Wm1 + bm1      via 8x mfma (K=64, H transposed through padded LDS)
//  v = relu(T)@Wm2 + bm2, quad shuffle-reduce; per-graph mean via block gacc.
// Layouts (verified docs): C/D col=lane&15,row=quad*4+reg; A/B [m|n=lane&15][k=quad*8+j].
__global__ __launch_bounds__(256) void k_tail_mfma(
    const half_t* __restrict__ Y, const half_t* __restrict__ W2t, const float* __restrict__ b2,
    const half_t* __restrict__ Wm1t, const float* __restrict__ bm1,
    const float* __restrict__ Wm2, const float* __restrict__ bm2,
    const int* __restrict__ nn_p, float* __restrict__ out, int N, int n_graphs)
{
    __shared__ float gacc[32];
    __shared__ __align__(16) half_t Hb[4][16][72];  // 16 nodes x 64 (+8 pad) per wave
    const int tid = threadIdx.x;
    if (tid < 32) gacc[tid] = 0.f;
    __syncthreads();
    const int wid = tid >> 6, lane = tid & 63;
    const int quad = lane >> 4, n16 = lane & 15;
    const int n0 = blockIdx.x * 64 + wid * 16;
    if (n0 < N) {
        const int nrow = min(n0 + n16, N - 1);
        half8 a1 = *(const half8*)(Y + (size_t)nrow * 32 + quad * 8);
        f32x4 acc1[4];
#pragma unroll
        for (int t = 0; t < 4; ++t) {
            half8 bf = *(const half8*)(W2t + (size_t)(t * 16 + n16) * 32 + quad * 8);
            f32x4 z = {0.f, 0.f, 0.f, 0.f};
            acc1[t] = __builtin_amdgcn_mfma_f32_16x16x32_f16(a1, bf, z, 0, 0, 0);
        }
        // relu + bias -> LDS (C-layout write)
#pragma unroll
        for (int t = 0; t < 4; ++t) {
            int c = t * 16 + n16;
            float bb = b2[c];
#pragma unroll
            for (int r = 0; r < 4; ++r)
                Hb[wid][quad * 4 + r][c] = (half_t)fmaxf(acc1[t][r] + bb, 0.f);
        }
        // A-layout read (wave-private; compiler inserts lgkm waits)
        half8 a2lo = *(const half8*)&Hb[wid][n16][quad * 8];
        half8 a2hi = *(const half8*)&Hb[wid][n16][32 + quad * 8];
        f32x4 acc2[4];
#pragma unroll
        for (int t = 0; t < 4; ++t) {
            half8 b0 = *(const half8*)(Wm1t + (size_t)(t * 16 + n16) * 64 + quad * 8);
            half8 b1 = *(const half8*)(Wm1t + (size_t)(t * 16 + n16) * 64 + 32 + quad * 8);
            f32x4 a = {0.f, 0.f, 0.f, 0.f};
            a = __builtin_amdgcn_mfma_f32_16x16x32_f16(a2lo, b0, a, 0, 0, 0);
            a = __builtin_amdgcn_mfma_f32_16x16x32_f16(a2hi, b1, a, 0, 0, 0);
            acc2[t] = a;
        }
        float vsum[4] = {0.f, 0.f, 0.f, 0.f};
#pragma unroll
        for (int t = 0; t < 4; ++t) {
            int c = t * 16 + n16;
            float bb = bm1[c], ww = Wm2[c];
#pragma unroll
            for (int r = 0; r < 4; ++r)
                vsum[r] += fmaxf(acc2[t][r] + bb, 0.f) * ww;
        }
#pragma unroll
        for (int m = 1; m < 16; m <<= 1) {
#pragma unroll
            for (int r = 0; r < 4; ++r) vsum[r] += __shfl_xor(vsum[r], m, 64);
        }
        if (n16 == 0) {
            const int nnv = nn_p[0];
            const float bm2v = bm2[0];
#pragma unroll
            for (int r = 0; r < 4; ++r) {
                int n = n0 + quad * 4 + r;
                if (n < N) {
                    int g = n / nnv;
                    if (g < 32) atomicAdd(&gacc[g], vsum[r] + bm2v);
                }
            }
        }
    }
    __syncthreads();
    if (tid < n_graphs && tid < 32) atomicAdd(&out[tid], gacc[tid] / (float)nn_p[0]);
}

// ---- fallback (atomic) path ----------------------------------------------
__global__ void k_zero_int(int* p, int n) {
    int i = blockIdx.x * blockDim.x + threadIdx.x;
    if (i < n) p[i] = 0;
}
__global__ void k_hist(const int* __restrict__ dst, int* __restrict__ deg, int E) {
    int e = blockIdx.x * blockDim.x + threadIdx.x;
    if (e < E) atomicAdd(&deg[dst[e]], 1);
}
__global__ void k_dinv(const int* __restrict__ deg, float* __restrict__ dinv, int n) {
    int i = blockIdx.x * blockDim.x + threadIdx.x;
    if (i < n) dinv[i] = rsqrtf(1.0f + (float)deg[i]);
}
__global__ __launch_bounds__(256) void k_gemm1f(
    const float* __restrict__ x, const float* __restrict__ W,
    const float* __restrict__ dinv, float* __restrict__ hs1, int N)
{
    __shared__ float Wl[128 * 32];
    __shared__ __align__(16) float Xl[8 * 132];
    const int tid = threadIdx.x;
    for (int i = tid; i < 128 * 32; i += 256) Wl[i] = W[i];
    const int node0 = blockIdx.x * 8;
    {
        int r = tid >> 5, c4 = tid & 31;
        int node = node0 + r;
        float4 v = make_float4(0.f, 0.f, 0.f, 0.f);
        if (node < N) v = ((const float4*)(x + (size_t)node * 128))[c4];
        *(float4*)&Xl[r * 132 + c4 * 4] = v;
    }
    __syncthreads();
    const int row = tid >> 5, f = tid & 31;
    float acc = 0.f;
#pragma unroll
    for (int k = 0; k < 128; k += 4) {
        float4 xv = *(const float4*)&Xl[row * 132 + k];
        acc += xv.x * Wl[(k + 0) * 32 + f];
        acc += xv.y * Wl[(k + 1) * 32 + f];
        acc += xv.z * Wl[(k + 2) * 32 + f];
        acc += xv.w * Wl[(k + 3) * 32 + f];
    }
    const int node = node0 + row;
    if (node < N) hs1[(size_t)node * 32 + f] = acc * dinv[node];
}
__global__ __launch_bounds__(256) void k_gemm2(
    const float* __restrict__ agg1, const float* __restrict__ W,
    const float* __restrict__ dinv, float* __restrict__ hs2, int N)
{
    __shared__ float Wl[32 * 64];
    __shared__ __align__(16) float Zl[4 * 36];
    const int tid = threadIdx.x;
    for (int i = tid; i < 32 * 64; i += 256) Wl[i] = W[i];
    const int node0 = blockIdx.x * 4;
    if (tid < 128) {
        int r = tid >> 5, c = tid & 31;
        int node = node0 + r;
        float v = 0.f;
        if (node < N) v = fmaxf(agg1[(size_t)node * 32 + c], 0.f);
        Zl[r * 36 + c] = v;
    }
    __syncthreads();
    const int row = tid >> 6, f = tid & 63;
    float acc = 0.f;
#pragma unroll
    for (int k = 0; k < 32; k += 4) {
        float4 zv = *(const float4*)&Zl[row * 36 + k];
        acc += zv.x * Wl[(k + 0) * 64 + f];
        acc += zv.y * Wl[(k + 1) * 64 + f];
        acc += zv.z * Wl[(k + 2) * 64 + f];
        acc += zv.w * Wl[(k + 3) * 64 + f];
    }
    int node = node0 + row;
    if (node < N) hs2[(size_t)node * 64 + f] = acc * dinv[node];
}
template <int F>
__global__ void k_agg_init(const float* __restrict__ hs, const float* __restrict__ b,
                           const float* __restrict__ dinv, float* __restrict__ agg, int N)
{
    long long t = (long long)blockIdx.x * blockDim.x + threadIdx.x;
    int n = (int)(t / F), f = (int)(t % F);
    if (n < N) agg[(size_t)n * F + f] = hs[(size_t)n * F + f] * dinv[n] + b[f];
}
template <int F>
__global__ void k_edge_atomic(const int* __restrict__ ei, const float* __restrict__ hs,
                              const float* __restrict__ dinv, float* __restrict__ agg, int E)
{
    long long tid = (long long)blockIdx.x * blockDim.x + threadIdx.x;
    int e = (int)(tid / F), f = (int)(tid % F);
    if (e < E) {
        int s = ei[e], d = ei[E + e];
        atomicAdd(&agg[(size_t)d * F + f], hs[(size_t)s * F + f] * dinv[d]);
    }
}
__global__ __launch_bounds__(256) void k_mlp(
    const float* __restrict__ agg2, const float* __restrict__ Wm1,
    const float* __restrict__ bm1, const float* __restrict__ Wm2,
    const float* __restrict__ bm2, float* __restrict__ vout, int N)
{
    __shared__ float Wl[64 * 64];
    __shared__ float W2l[64];
    __shared__ __align__(16) float Zl[4][64];
    const int tid = threadIdx.x;
    for (int i = tid; i < 64 * 64; i += 256) Wl[i] = Wm1[i];
    if (tid < 64) W2l[tid] = Wm2[tid];
    const int wid = tid >> 6, lane = tid & 63;
    const int node = blockIdx.x * 4 + wid;
    float zv = 0.f;
    if (node < N) zv = fmaxf(agg2[(size_t)node * 64 + lane], 0.f);
    Zl[wid][lane] = zv;
    __syncthreads();
    float t = bm1[lane];
#pragma unroll
    for (int k = 0; k < 64; k += 4) {
        float4 z4 = *(const float4*)&Zl[wid][k];
        t += z4.x * Wl[(k + 0) * 64 + lane];
        t += z4.y * Wl[(k + 1) * 64 + lane];
        t += z4.z * Wl[(k + 2) * 64 + lane];
        t += z4.w * Wl[(k + 3) * 64 + lane];
    }
    t = fmaxf(t, 0.f);
    float val = t * W2l[lane];
#pragma unroll
    for (int off = 32; off > 0; off >>= 1) val += __shfl_down(val, off, 64);
    if (lane == 0 && node < N) vout[node] = val + bm2[0];
}
__global__ void k_reduce(const float* __restrict__ v, const int* __restrict__ num_nodes_p,
                         float* out, int N, int n_graphs)
{
    __shared__ float acc[32];
    int tid = threadIdx.x;
    if (tid < n_graphs) acc[tid] = 0.f;
    __syncthreads();
    int i = blockIdx.x * blockDim.x + tid;
    int nn = num_nodes_p[0];
    if (i < N) {
        int g = i / nn;
        if (g < n_graphs) atomicAdd(&acc[g], v[i]);
    }
    __syncthreads();
    if (tid < n_graphs) atomicAdd(&out[tid], acc[tid] / (float)nn);
}
// ---------------------------------------------------------------------------

extern "C" void kernel_launch(void* const* d_in, const int* in_sizes, int n_in,
                              void* d_out, int out_size, void* d_ws, size_t ws_size,
                              hipStream_t stream)
{
    const float* x   = (const float*)d_in[0];
    const float* W1  = (const float*)d_in[1];
    const float* b1  = (const float*)d_in[2];
    const float* W2  = (const float*)d_in[3];
    const float* b2  = (const float*)d_in[4];
    const float* Wm1 = (const float*)d_in[5];
    const float* bm1 = (const float*)d_in[6];
    const float* Wm2 = (const float*)d_in[7];
    const float* bm2 = (const float*)d_in[8];
    const int*   ei  = (const int*)d_in[9];
    const int*   nn  = (const int*)d_in[10];
    const int N = in_sizes[0] / 128;
    const int E = in_sizes[9] / 2;
    float* out = (float*)d_out;

    const int NB = (N + BKN - 1) / BKN;
    const int nblk = (E + CHUNK - 1) / CHUNK;
    const long long T = (long long)NB * nblk;
    const int nb1 = (int)((T + 255) / 256);
    // ints: table T + S (T+1) + bsums 1024 + codes E + esrc E + row_start N+1
    //     + dinv N + fp16 feats 48N + W2t/Wm1t 3072
    const size_t need_ints = (size_t)T + (size_t)(T + 1) + 1024
                           + (size_t)E + (size_t)E + (size_t)(N + 1)
                           + (size_t)N + 48ull * N + 3072;
    const bool use_new = (N <= 131072) && (T <= 262144) && (nb1 <= 1024)
                       && (out_size <= 32)
                       && (ws_size >= need_ints * sizeof(int));

    k_zero_out<<<1, 64, 0, stream>>>(out, out_size);

    if (use_new) {
        int*    table     = (int*)d_ws;                  // T
        int*    S         = table + T;                   // T+1
        int*    bsums     = S + (T + 1);                 // 1024
        int*    codes     = bsums + 1024;                // E
        int*    esrc      = codes + E;                   // E
        int*    row_start = esrc + E;                    // N+1
        float*  dinv      = (float*)(row_start + N + 1); // N
        half_t* hs1h      = (half_t*)(dinv + N);         // 32N halves
        half_t* Zs        = hs1h + 32 * (size_t)N;       // 32N halves
        half_t* Y         = Zs + 32 * (size_t)N;         // 32N halves
        half_t* W2t       = Y + 32 * (size_t)N;          // 2048 halves
        half_t* Wm1t      = W2t + 2048;                  // 4096 halves

        k_count_coarse<<<nblk, 256, 0, stream>>>(ei + E, table, E, nblk, NB);
        k_scan1<<<nb1, 256, 0, stream>>>(table, S, bsums, (int)T);
        k_scan2<<<1, 1024, 0, stream>>>(bsums, nb1);
        k_scan3<<<nb1, 256, 0, stream>>>(S, bsums, (int)T);
        k_scatter2<<<nblk, 256, 0, stream>>>(ei, S, codes, E, nblk, NB);
        k_fine<<<NB, 256, 0, stream>>>(codes, S, esrc, row_start, dinv, nblk, N, E, NB);
        k_prep<<<16, 256, 0, stream>>>(W2, Wm1, W2t, Wm1t);
        k_gemm1<<<(N + 7) / 8, 256, 0, stream>>>(x, W1, dinv, hs1h, N);
        k_aggh<true><<<(N + 63) / 64, 256, 0, stream>>>(row_start, esrc, hs1h, b1, dinv, Zs, N);
        k_aggh<false><<<(N + 63) / 64, 256, 0, stream>>>(row_start, esrc, Zs, b1, dinv, Y, N);
        k_tail_mfma<<<(N + 63) / 64, 256, 0, stream>>>(Y, W2t, b2, Wm1t, bm1, Wm2, bm2,
                                                       nn, out, N, out_size);
    } else {
        // fallback: fp32 atomic scatter path
        const size_t Ns = (size_t)N;
        float* dinv = (float*)d_ws;
        float* B    = dinv + N;
        float* hs1  = B;
        float* agg1 = B + 32 * Ns;
        float* hs2  = B + 64 * Ns;
        float* agg2 = B + 128 * Ns;
        float* vtmp = B;
        int*   deg  = (int*)B;

        const int nb = (N + 255) / 256;
        k_zero_int<<<nb, 256, 0, stream>>>(deg, N);
        k_hist<<<(E + 255) / 256, 256, 0, stream>>>(ei + E, deg, E);
        k_dinv<<<nb, 256, 0, stream>>>(deg, dinv, N);
        k_gemm1f<<<(N + 7) / 8, 256, 0, stream>>>(x, W1, dinv, hs1, N);
        {
            long long t = (long long)N * 32;
            k_agg_init<32><<<(unsigned)((t + 255) / 256), 256, 0, stream>>>(hs1, b1, dinv, agg1, N);
            t = (long long)E * 32;
            k_edge_atomic<32><<<(unsigned)((t + 255) / 256), 256, 0, stream>>>(ei, hs1, dinv, agg1, E);
        }
        k_gemm2<<<(N + 3) / 4, 256, 0, stream>>>(agg1, W2, dinv, hs2, N);
        {
            long long t = (long long)N * 64;
            k_agg_init<64><<<(unsigned)((t + 255) / 256), 256, 0, stream>>>(hs2, b2, dinv, agg2, N);
            t = (long long)E * 64;
            k_edge_atomic<64><<<(unsigned)((t + 255) / 256), 256, 0, stream>>>(ei, hs2, dinv, agg2, E);
        }
        k_mlp<<<(N + 3) / 4, 256, 0, stream>>>(agg2, Wm1, bm1, Wm2, bm2, vtmp, N);
        k_reduce<<<nb, 256, 0, stream>>>(vtmp, nn, out, N, out_size);
    }
}

// Round 7
// 295.787 us; speedup vs baseline: 4.4716x; 1.1186x over previous
//
#include <hip/hip_runtime.h>

// ---------------------------------------------------------------------------
// CriticNetwork: 2x GCNConv (relu) + MLP head + per-graph mean.
// Round 7: MFMA gemm1 (fp16 16x16x32, x converted in-register, W1 pre-
// transposed to fp16); scatter2 preloads per-block cursor bases into LDS
// (kills the per-edge global S read + base add). Rest unchanged from R6.
// ---------------------------------------------------------------------------

typedef _Float16 half_t;
typedef __attribute__((ext_vector_type(8))) _Float16 half8;
typedef __attribute__((ext_vector_type(4))) float f32x4;

#define CHUNK 8192    // edges per sort block
#define BKN   128     // nodes per coarse bucket
#define NBMAX 1024    // max coarse buckets (N <= 131072)

__global__ void k_zero_out(float* out, int n) {
    int i = blockIdx.x * blockDim.x + threadIdx.x;
    if (i < n) out[i] = 0.0f;
}

// ---- coarse counting sort ------------------------------------------------

__global__ __launch_bounds__(256) void k_count_coarse(
    const int* __restrict__ dst, int* __restrict__ table, int E, int nblk, int NB)
{
    __shared__ int cnt[NBMAX];
    const int tid = threadIdx.x;
    for (int i = tid; i < NB; i += 256) cnt[i] = 0;
    __syncthreads();
    const int base = blockIdx.x * CHUNK;
    const int lim = min(CHUNK, E - base);
    if (lim == CHUNK) {
        const int4* d4 = (const int4*)(dst + base);
        for (int i = tid; i < CHUNK / 4; i += 256) {
            int4 v = d4[i];
            atomicAdd(&cnt[v.x >> 7], 1);
            atomicAdd(&cnt[v.y >> 7], 1);
            atomicAdd(&cnt[v.z >> 7], 1);
            atomicAdd(&cnt[v.w >> 7], 1);
        }
    } else {
        for (int i = tid; i < lim; i += 256) atomicAdd(&cnt[dst[base + i] >> 7], 1);
    }
    __syncthreads();
    for (int b = tid; b < NB; b += 256) table[b * nblk + blockIdx.x] = cnt[b];
}

__global__ __launch_bounds__(256) void k_scan1(const int* __restrict__ cnts, int* __restrict__ S,
                                               int* __restrict__ bsums, int T) {
    __shared__ int sh[256];
    int t = threadIdx.x;
    int i = blockIdx.x * 256 + t;
    int v = (i < T) ? cnts[i] : 0;
    sh[t] = v;
    __syncthreads();
    for (int off = 1; off < 256; off <<= 1) {
        int tv = (t >= off) ? sh[t - off] : 0;
        __syncthreads();
        sh[t] += tv;
        __syncthreads();
    }
    if (i < T) S[i + 1] = sh[t];
    if (t == 255) bsums[blockIdx.x] = sh[255];
}

// exclusive scan of up to 1024 block sums
__global__ __launch_bounds__(1024) void k_scan2(int* bs, int nb) {
    __shared__ int sh[1024];
    int t = threadIdx.x;
    int v = (t < nb) ? bs[t] : 0;
    sh[t] = v;
    __syncthreads();
    for (int off = 1; off < 1024; off <<= 1) {
        int tv = (t >= off) ? sh[t - off] : 0;
        __syncthreads();
        sh[t] += tv;
        __syncthreads();
    }
    if (t < nb) bs[t] = sh[t] - v;  // exclusive
}

__global__ void k_scan3(int* __restrict__ S, const int* __restrict__ bs, int T) {
    int i = blockIdx.x * blockDim.x + threadIdx.x;
    if (i < T) S[i + 1] += bs[i >> 8];
    if (i == 0) S[0] = 0;
}

// scatter: per-block cursor bases preloaded into LDS; per edge = one LDS
// atomic (returns absolute position) + one global store.
__global__ __launch_bounds__(256) void k_scatter2(
    const int* __restrict__ ei, const int* __restrict__ S,
    int* __restrict__ codes, int E, int nblk, int NB)
{
    __shared__ int cur[NBMAX];
    const int tid = threadIdx.x;
    for (int i = tid; i < NB; i += 256) cur[i] = S[i * nblk + blockIdx.x];
    __syncthreads();
    const int base = blockIdx.x * CHUNK;
    const int lim = min(CHUNK, E - base);
    if (lim == CHUNK) {
        const int4* s4 = (const int4*)(ei + base);
        const int4* d4 = (const int4*)(ei + E + base);
        for (int i = tid; i < CHUNK / 4; i += 256) {
            int4 sv = s4[i], dv = d4[i];
            {
                int pos = atomicAdd(&cur[dv.x >> 7], 1);
                codes[pos] = ((dv.x & 127) << 17) | sv.x;
            }
            {
                int pos = atomicAdd(&cur[dv.y >> 7], 1);
                codes[pos] = ((dv.y & 127) << 17) | sv.y;
            }
            {
                int pos = atomicAdd(&cur[dv.z >> 7], 1);
                codes[pos] = ((dv.z & 127) << 17) | sv.z;
            }
            {
                int pos = atomicAdd(&cur[dv.w >> 7], 1);
                codes[pos] = ((dv.w & 127) << 17) | sv.w;
            }
        }
    } else {
        for (int i = tid; i < lim; i += 256) {
            int e = base + i;
            int s = ei[e], d = ei[E + e];
            int pos = atomicAdd(&cur[d >> 7], 1);
            codes[pos] = ((d & 127) << 17) | s;
        }
    }
}

// per-bucket fine CSR: degree count -> LDS scan -> dst-sorted esrc + row_start + dinv
__global__ __launch_bounds__(256) void k_fine(
    const int* __restrict__ codes, const int* __restrict__ S,
    int* __restrict__ esrc, int* __restrict__ row_start,
    float* __restrict__ dinv, int nblk, int N, int E, int NB)
{
    __shared__ int cnt[BKN];
    __shared__ int sh[BKN];
    __shared__ int cur[BKN];
    const int tid = threadIdx.x;
    if (tid < BKN) cnt[tid] = 0;
    __syncthreads();
    const int b = blockIdx.x;
    const int beg = S[b * nblk], end = S[(b + 1) * nblk];
    for (int e = beg + tid; e < end; e += 256) atomicAdd(&cnt[codes[e] >> 17], 1);
    __syncthreads();
    if (tid < BKN) sh[tid] = cnt[tid];
    __syncthreads();
    for (int off = 1; off < BKN; off <<= 1) {
        int tv = (tid >= off && tid < BKN) ? sh[tid - off] : 0;
        __syncthreads();
        if (tid < BKN) sh[tid] += tv;
        __syncthreads();
    }
    if (tid < BKN) {
        int fs = beg + sh[tid] - cnt[tid];   // exclusive prefix, global offset
        cur[tid] = fs;
        int n = b * BKN + tid;
        if (n < N) {
            row_start[n] = fs;
            dinv[n] = rsqrtf(1.0f + (float)cnt[tid]);
        }
    }
    if (b == NB - 1 && tid == 0) row_start[N] = E;
    __syncthreads();
    for (int e = beg + tid; e < end; e += 256) {
        int c = codes[e];
        int pos = atomicAdd(&cur[c >> 17], 1);
        esrc[pos] = c & 0x1FFFF;
    }
}

// ---- dense compute -------------------------------------------------------

// transpose+convert weights to fp16:
//  W1t[32][128] from W1[128][32]; W2t[64][32] from W2[32][64]; Wm1t[64][64]
__global__ __launch_bounds__(256) void k_prep(
    const float* __restrict__ W1, const float* __restrict__ W2, const float* __restrict__ Wm1,
    half_t* __restrict__ W1t, half_t* __restrict__ W2t, half_t* __restrict__ Wm1t)
{
    int i = blockIdx.x * 256 + threadIdx.x;
    if (i < 128 * 32) { int k = i >> 5, c = i & 31; W1t[c * 128 + k] = (half_t)W1[i]; }
    if (i < 32 * 64)  { int k = i >> 6, c = i & 63; W2t[c * 32 + k]  = (half_t)W2[i]; }
    if (i < 64 * 64)  { int k = i >> 6, c = i & 63; Wm1t[c * 64 + k] = (half_t)Wm1[i]; }
}

// hs1 = fp16( (x @ W1) * dinv ) via MFMA. One wave = 16 nodes, K=128 in 4
// chunks, 2 feature tiles. A converted fp32->fp16 in-register.
__global__ __launch_bounds__(256) void k_gemm1_mfma(
    const float* __restrict__ x, const half_t* __restrict__ W1t,
    const float* __restrict__ dinv, half_t* __restrict__ hs1, int N)
{
    const int tid = threadIdx.x;
    const int wid = tid >> 6, lane = tid & 63;
    const int quad = lane >> 4, n16 = lane & 15;
    const int n0 = blockIdx.x * 64 + wid * 16;
    if (n0 >= N) return;
    const int nrow = min(n0 + n16, N - 1);
    const float* xr = x + (size_t)nrow * 128;
    f32x4 acc0 = {0.f, 0.f, 0.f, 0.f}, acc1 = {0.f, 0.f, 0.f, 0.f};
#pragma unroll
    for (int kc = 0; kc < 4; ++kc) {
        float4 f0 = *(const float4*)(xr + kc * 32 + quad * 8);
        float4 f1 = *(const float4*)(xr + kc * 32 + quad * 8 + 4);
        half8 a;
        a[0] = (half_t)f0.x; a[1] = (half_t)f0.y; a[2] = (half_t)f0.z; a[3] = (half_t)f0.w;
        a[4] = (half_t)f1.x; a[5] = (half_t)f1.y; a[6] = (half_t)f1.z; a[7] = (half_t)f1.w;
        half8 b0 = *(const half8*)(W1t + (size_t)n16 * 128 + kc * 32 + quad * 8);
        half8 b1 = *(const half8*)(W1t + (size_t)(16 + n16) * 128 + kc * 32 + quad * 8);
        acc0 = __builtin_amdgcn_mfma_f32_16x16x32_f16(a, b0, acc0, 0, 0, 0);
        acc1 = __builtin_amdgcn_mfma_f32_16x16x32_f16(a, b1, acc1, 0, 0, 0);
    }
    // C/D: col(feature)=n16, row(node)=quad*4+r
#pragma unroll
    for (int r = 0; r < 4; ++r) {
        int n = n0 + quad * 4 + r;
        if (n < N) {
            float dv = dinv[n];
            hs1[(size_t)n * 32 + n16]      = (half_t)(acc0[r] * dv);
            hs1[(size_t)n * 32 + 16 + n16] = (half_t)(acc1[r] * dv);
        }
    }
}

// node-parallel fp16 CSR gather-reduce (round 5, unchanged)
template <bool L1>
__global__ __launch_bounds__(256) void k_aggh(
    const int* __restrict__ row_start, const int* __restrict__ esrc,
    const half_t* __restrict__ IN, const float* __restrict__ bias,
    const float* __restrict__ dinv, half_t* __restrict__ OUT, int N)
{
    const int tid = threadIdx.x;
    const int g = tid >> 2, l = tid & 3;       // 64 nodes x 4 lanes
    const int n = blockIdx.x * 64 + g;
    if (n >= N) return;
    const half8* IN8 = (const half8*)IN;       // row = 4 x half8
    const int beg = row_start[n], end = row_start[n + 1];
    half8 self = IN8[(size_t)n * 4 + l];
    float acc[8];
#pragma unroll
    for (int j = 0; j < 8; ++j) acc[j] = (float)self[j];
    int e = beg;
    for (; e + 3 < end; e += 4) {
        int s0 = esrc[e], s1 = esrc[e + 1], s2 = esrc[e + 2], s3 = esrc[e + 3];
        half8 v0 = IN8[(size_t)s0 * 4 + l];
        half8 v1 = IN8[(size_t)s1 * 4 + l];
        half8 v2 = IN8[(size_t)s2 * 4 + l];
        half8 v3 = IN8[(size_t)s3 * 4 + l];
#pragma unroll
        for (int j = 0; j < 8; ++j)
            acc[j] += ((float)v0[j] + (float)v1[j]) + ((float)v2[j] + (float)v3[j]);
    }
    for (; e < end; ++e) {
        half8 v = IN8[(size_t)esrc[e] * 4 + l];
#pragma unroll
        for (int j = 0; j < 8; ++j) acc[j] += (float)v[j];
    }
    const float dv = dinv[n];
    half8 o;
    if (L1) {
#pragma unroll
        for (int j = 0; j < 8; ++j) {
            float bb = bias[l * 8 + j];
            o[j] = (half_t)(fmaxf(dv * acc[j] + bb, 0.f) * dv);
        }
    } else {
#pragma unroll
        for (int j = 0; j < 8; ++j) o[j] = (half_t)(dv * acc[j]);
    }
    ((half8*)OUT)[(size_t)n * 4 + l] = o;
}

// MFMA tail (round 6, unchanged)
__global__ __launch_bounds__(256) void k_tail_mfma(
    const half_t* __restrict__ Y, const half_t* __restrict__ W2t, const float* __restrict__ b2,
    const half_t* __restrict__ Wm1t, const float* __restrict__ bm1,
    const float* __restrict__ Wm2, const float* __restrict__ bm2,
    const int* __restrict__ nn_p, float* __restrict__ out, int N, int n_graphs)
{
    __shared__ float gacc[32];
    __shared__ __align__(16) half_t Hb[4][16][72];
    const int tid = threadIdx.x;
    if (tid < 32) gacc[tid] = 0.f;
    __syncthreads();
    const int wid = tid >> 6, lane = tid & 63;
    const int quad = lane >> 4, n16 = lane & 15;
    const int n0 = blockIdx.x * 64 + wid * 16;
    if (n0 < N) {
        const int nrow = min(n0 + n16, N - 1);
        half8 a1 = *(const half8*)(Y + (size_t)nrow * 32 + quad * 8);
        f32x4 acc1[4];
#pragma unroll
        for (int t = 0; t < 4; ++t) {
            half8 bf = *(const half8*)(W2t + (size_t)(t * 16 + n16) * 32 + quad * 8);
            f32x4 z = {0.f, 0.f, 0.f, 0.f};
            acc1[t] = __builtin_amdgcn_mfma_f32_16x16x32_f16(a1, bf, z, 0, 0, 0);
        }
#pragma unroll
        for (int t = 0; t < 4; ++t) {
            int c = t * 16 + n16;
            float bb = b2[c];
#pragma unroll
            for (int r = 0; r < 4; ++r)
                Hb[wid][quad * 4 + r][c] = (half_t)fmaxf(acc1[t][r] + bb, 0.f);
        }
        half8 a2lo = *(const half8*)&Hb[wid][n16][quad * 8];
        half8 a2hi = *(const half8*)&Hb[wid][n16][32 + quad * 8];
        f32x4 acc2[4];
#pragma unroll
        for (int t = 0; t < 4; ++t) {
            half8 b0 = *(const half8*)(Wm1t + (size_t)(t * 16 + n16) * 64 + quad * 8);
            half8 b1 = *(const half8*)(Wm1t + (size_t)(t * 16 + n16) * 64 + 32 + quad * 8);
            f32x4 a = {0.f, 0.f, 0.f, 0.f};
            a = __builtin_amdgcn_mfma_f32_16x16x32_f16(a2lo, b0, a, 0, 0, 0);
            a = __builtin_amdgcn_mfma_f32_16x16x32_f16(a2hi, b1, a, 0, 0, 0);
            acc2[t] = a;
        }
        float vsum[4] = {0.f, 0.f, 0.f, 0.f};
#pragma unroll
        for (int t = 0; t < 4; ++t) {
            int c = t * 16 + n16;
            float bb = bm1[c], ww = Wm2[c];
#pragma unroll
            for (int r = 0; r < 4; ++r)
                vsum[r] += fmaxf(acc2[t][r] + bb, 0.f) * ww;
        }
#pragma unroll
        for (int m = 1; m < 16; m <<= 1) {
#pragma unroll
            for (int r = 0; r < 4; ++r) vsum[r] += __shfl_xor(vsum[r], m, 64);
        }
        if (n16 == 0) {
            const int nnv = nn_p[0];
            const float bm2v = bm2[0];
#pragma unroll
            for (int r = 0; r < 4; ++r) {
                int n = n0 + quad * 4 + r;
                if (n < N) {
                    int g = n / nnv;
                    if (g < 32) atomicAdd(&gacc[g], vsum[r] + bm2v);
                }
            }
        }
    }
    __syncthreads();
    if (tid < n_graphs && tid < 32) atomicAdd(&out[tid], gacc[tid] / (float)nn_p[0]);
}

// ---- fallback (atomic) path ----------------------------------------------
__global__ void k_zero_int(int* p, int n) {
    int i = blockIdx.x * blockDim.x + threadIdx.x;
    if (i < n) p[i] = 0;
}
__global__ void k_hist(const int* __restrict__ dst, int* __restrict__ deg, int E) {
    int e = blockIdx.x * blockDim.x + threadIdx.x;
    if (e < E) atomicAdd(&deg[dst[e]], 1);
}
__global__ void k_dinv(const int* __restrict__ deg, float* __restrict__ dinv, int n) {
    int i = blockIdx.x * blockDim.x + threadIdx.x;
    if (i < n) dinv[i] = rsqrtf(1.0f + (float)deg[i]);
}
__global__ __launch_bounds__(256) void k_gemm1f(
    const float* __restrict__ x, const float* __restrict__ W,
    const float* __restrict__ dinv, float* __restrict__ hs1, int N)
{
    __shared__ float Wl[128 * 32];
    __shared__ __align__(16) float Xl[8 * 132];
    const int tid = threadIdx.x;
    for (int i = tid; i < 128 * 32; i += 256) Wl[i] = W[i];
    const int node0 = blockIdx.x * 8;
    {
        int r = tid >> 5, c4 = tid & 31;
        int node = node0 + r;
        float4 v = make_float4(0.f, 0.f, 0.f, 0.f);
        if (node < N) v = ((const float4*)(x + (size_t)node * 128))[c4];
        *(float4*)&Xl[r * 132 + c4 * 4] = v;
    }
    __syncthreads();
    const int row = tid >> 5, f = tid & 31;
    float acc = 0.f;
#pragma unroll
    for (int k = 0; k < 128; k += 4) {
        float4 xv = *(const float4*)&Xl[row * 132 + k];
        acc += xv.x * Wl[(k + 0) * 32 + f];
        acc += xv.y * Wl[(k + 1) * 32 + f];
        acc += xv.z * Wl[(k + 2) * 32 + f];
        acc += xv.w * Wl[(k + 3) * 32 + f];
    }
    const int node = node0 + row;
    if (node < N) hs1[(size_t)node * 32 + f] = acc * dinv[node];
}
__global__ __launch_bounds__(256) void k_gemm2(
    const float* __restrict__ agg1, const float* __restrict__ W,
    const float* __restrict__ dinv, float* __restrict__ hs2, int N)
{
    __shared__ float Wl[32 * 64];
    __shared__ __align__(16) float Zl[4 * 36];
    const int tid = threadIdx.x;
    for (int i = tid; i < 32 * 64; i += 256) Wl[i] = W[i];
    const int node0 = blockIdx.x * 4;
    if (tid < 128) {
        int r = tid >> 5, c = tid & 31;
        int node = node0 + r;
        float v = 0.f;
        if (node < N) v = fmaxf(agg1[(size_t)node * 32 + c], 0.f);
        Zl[r * 36 + c] = v;
    }
    __syncthreads();
    const int row = tid >> 6, f = tid & 63;
    float acc = 0.f;
#pragma unroll
    for (int k = 0; k < 32; k += 4) {
        float4 zv = *(const float4*)&Zl[row * 36 + k];
        acc += zv.x * Wl[(k + 0) * 64 + f];
        acc += zv.y * Wl[(k + 1) * 64 + f];
        acc += zv.z * Wl[(k + 2) * 64 + f];
        acc += zv.w * Wl[(k + 3) * 64 + f];
    }
    int node = node0 + row;
    if (node < N) hs2[(size_t)node * 64 + f] = acc * dinv[node];
}
template <int F>
__global__ void k_agg_init(const float* __restrict__ hs, const float* __restrict__ b,
                           const float* __restrict__ dinv, float* __restrict__ agg, int N)
{
    long long t = (long long)blockIdx.x * blockDim.x + threadIdx.x;
    int n = (int)(t / F), f = (int)(t % F);
    if (n < N) agg[(size_t)n * F + f] = hs[(size_t)n * F + f] * dinv[n] + b[f];
}
template <int F>
__global__ void k_edge_atomic(const int* __restrict__ ei, const float* __restrict__ hs,
                              const float* __restrict__ dinv, float* __restrict__ agg, int E)
{
    long long tid = (long long)blockIdx.x * blockDim.x + threadIdx.x;
    int e = (int)(tid / F), f = (int)(tid % F);
    if (e < E) {
        int s = ei[e], d = ei[E + e];
        atomicAdd(&agg[(size_t)d * F + f], hs[(size_t)s * F + f] * dinv[d]);
    }
}
__global__ __launch_bounds__(256) void k_mlp(
    const float* __restrict__ agg2, const float* __restrict__ Wm1,
    const float* __restrict__ bm1, const float* __restrict__ Wm2,
    const float* __restrict__ bm2, float* __restrict__ vout, int N)
{
    __shared__ float Wl[64 * 64];
    __shared__ float W2l[64];
    __shared__ __align__(16) float Zl[4][64];
    const int tid = threadIdx.x;
    for (int i = tid; i < 64 * 64; i += 256) Wl[i] = Wm1[i];
    if (tid < 64) W2l[tid] = Wm2[tid];
    const int wid = tid >> 6, lane = tid & 63;
    const int node = blockIdx.x * 4 + wid;
    float zv = 0.f;
    if (node < N) zv = fmaxf(agg2[(size_t)node * 64 + lane], 0.f);
    Zl[wid][lane] = zv;
    __syncthreads();
    float t = bm1[lane];
#pragma unroll
    for (int k = 0; k < 64; k += 4) {
        float4 z4 = *(const float4*)&Zl[wid][k];
        t += z4.x * Wl[(k + 0) * 64 + lane];
        t += z4.y * Wl[(k + 1) * 64 + lane];
        t += z4.z * Wl[(k + 2) * 64 + lane];
        t += z4.w * Wl[(k + 3) * 64 + lane];
    }
    t = fmaxf(t, 0.f);
    float val = t * W2l[lane];
#pragma unroll
    for (int off = 32; off > 0; off >>= 1) val += __shfl_down(val, off, 64);
    if (lane == 0 && node < N) vout[node] = val + bm2[0];
}
__global__ void k_reduce(const float* __restrict__ v, const int* __restrict__ num_nodes_p,
                         float* out, int N, int n_graphs)
{
    __shared__ float acc[32];
    int tid = threadIdx.x;
    if (tid < n_graphs) acc[tid] = 0.f;
    __syncthreads();
    int i = blockIdx.x * blockDim.x + tid;
    int nn = num_nodes_p[0];
    if (i < N) {
        int g = i / nn;
        if (g < n_graphs) atomicAdd(&acc[g], v[i]);
    }
    __syncthreads();
    if (tid < n_graphs) atomicAdd(&out[tid], acc[tid] / (float)nn);
}
// ---------------------------------------------------------------------------

extern "C" void kernel_launch(void* const* d_in, const int* in_sizes, int n_in,
                              void* d_out, int out_size, void* d_ws, size_t ws_size,
                              hipStream_t stream)
{
    const float* x   = (const float*)d_in[0];
    const float* W1  = (const float*)d_in[1];
    const float* b1  = (const float*)d_in[2];
    const float* W2  = (const float*)d_in[3];
    const float* b2  = (const float*)d_in[4];
    const float* Wm1 = (const float*)d_in[5];
    const float* bm1 = (const float*)d_in[6];
    const float* Wm2 = (const float*)d_in[7];
    const float* bm2 = (const float*)d_in[8];
    const int*   ei  = (const int*)d_in[9];
    const int*   nn  = (const int*)d_in[10];
    const int N = in_sizes[0] / 128;
    const int E = in_sizes[9] / 2;
    float* out = (float*)d_out;

    const int NB = (N + BKN - 1) / BKN;
    const int nblk = (E + CHUNK - 1) / CHUNK;
    const long long T = (long long)NB * nblk;
    const int nb1 = (int)((T + 255) / 256);
    // ints: table T + S (T+1) + bsums 1024 + codes E + esrc E + row_start N+1
    //     + dinv N + fp16 feats 48N + W1t/W2t/Wm1t fp16 (2048+1024+2048 ints)
    const size_t need_ints = (size_t)T + (size_t)(T + 1) + 1024
                           + (size_t)E + (size_t)E + (size_t)(N + 1)
                           + (size_t)N + 48ull * N + 5120;
    const bool use_new = (N <= 131072) && (T <= 262144) && (nb1 <= 1024)
                       && (out_size <= 32)
                       && (ws_size >= need_ints * sizeof(int));

    k_zero_out<<<1, 64, 0, stream>>>(out, out_size);

    if (use_new) {
        int*    table     = (int*)d_ws;                  // T
        int*    S         = table + T;                   // T+1
        int*    bsums     = S + (T + 1);                 // 1024
        int*    codes     = bsums + 1024;                // E
        int*    esrc      = codes + E;                   // E
        int*    row_start = esrc + E;                    // N+1
        float*  dinv      = (float*)(row_start + N + 1); // N
        half_t* hs1h      = (half_t*)(dinv + N);         // 32N halves
        half_t* Zs        = hs1h + 32 * (size_t)N;       // 32N halves
        half_t* Y         = Zs + 32 * (size_t)N;         // 32N halves
        half_t* W1t       = Y + 32 * (size_t)N;          // 4096 halves
        half_t* W2t       = W1t + 4096;                  // 2048 halves
        half_t* Wm1t      = W2t + 2048;                  // 4096 halves

        k_count_coarse<<<nblk, 256, 0, stream>>>(ei + E, table, E, nblk, NB);
        k_scan1<<<nb1, 256, 0, stream>>>(table, S, bsums, (int)T);
        k_scan2<<<1, 1024, 0, stream>>>(bsums, nb1);
        k_scan3<<<nb1, 256, 0, stream>>>(S, bsums, (int)T);
        k_scatter2<<<nblk, 256, 0, stream>>>(ei, S, codes, E, nblk, NB);
        k_fine<<<NB, 256, 0, stream>>>(codes, S, esrc, row_start, dinv, nblk, N, E, NB);
        k_prep<<<16, 256, 0, stream>>>(W1, W2, Wm1, W1t, W2t, Wm1t);
        k_gemm1_mfma<<<(N + 63) / 64, 256, 0, stream>>>(x, W1t, dinv, hs1h, N);
        k_aggh<true><<<(N + 63) / 64, 256, 0, stream>>>(row_start, esrc, hs1h, b1, dinv, Zs, N);
        k_aggh<false><<<(N + 63) / 64, 256, 0, stream>>>(row_start, esrc, Zs, b1, dinv, Y, N);
        k_tail_mfma<<<(N + 63) / 64, 256, 0, stream>>>(Y, W2t, b2, Wm1t, bm1, Wm2, bm2,
                                                       nn, out, N, out_size);
    } else {
        // fallback: fp32 atomic scatter path
        const size_t Ns = (size_t)N;
        float* dinv = (float*)d_ws;
        float* B    = dinv + N;
        float* hs1  = B;
        float* agg1 = B + 32 * Ns;
        float* hs2  = B + 64 * Ns;
        float* agg2 = B + 128 * Ns;
        float* vtmp = B;
        int*   deg  = (int*)B;

        const int nb = (N + 255) / 256;
        k_zero_int<<<nb, 256, 0, stream>>>(deg, N);
        k_hist<<<(E + 255) / 256, 256, 0, stream>>>(ei + E, deg, E);
        k_dinv<<<nb, 256, 0, stream>>>(deg, dinv, N);
        k_gemm1f<<<(N + 7) / 8, 256, 0, stream>>>(x, W1, dinv, hs1, N);
        {
            long long t = (long long)N * 32;
            k_agg_init<32><<<(unsigned)((t + 255) / 256), 256, 0, stream>>>(hs1, b1, dinv, agg1, N);
            t = (long long)E * 32;
            k_edge_atomic<32><<<(unsigned)((t + 255) / 256), 256, 0, stream>>>(ei, hs1, dinv, agg1, E);
        }
        k_gemm2<<<(N + 3) / 4, 256, 0, stream>>>(agg1, W2, dinv, hs2, N);
        {
            long long t = (long long)N * 64;
            k_agg_init<64><<<(unsigned)((t + 255) / 256), 256, 0, stream>>>(hs2, b2, dinv, agg2, N);
            t = (long long)E * 64;
            k_edge_atomic<64><<<(unsigned)((t + 255) / 256), 256, 0, stream>>>(ei, hs2, dinv, agg2, E);
        }
        k_mlp<<<(N + 3) / 4, 256, 0, stream>>>(agg2, Wm1, bm1, Wm2, bm2, vtmp, N);
        k_reduce<<<nb, 256, 0, stream>>>(vtmp, nn, out, N, out_size);
    }
}